// Round 12
// baseline (768.676 us; speedup 1.0000x reference)
//
#include <hip/hip_runtime.h>
#include <math.h>

#define BN 8
#define TN 1024
#define HN 192
#define NHN 2
#define KCN 96
#define LN 6
#define FFNN 768
#define OUTN 192
#define QSTR 104  // kt/rbt LDS row stride in shorts: 13 granules (odd) -> conflict-free b128
#define GSTR 200  // K=192 GEMM LDS row stride (192 data + pad): 25 granules (odd)
#define M0S 12.0f // fixed softmax shift: scores are O(1); exp(s-12) safe to s~100

typedef short bfrag __attribute__((ext_vector_type(8)));
typedef float f32x4 __attribute__((ext_vector_type(4)));

__device__ __forceinline__ short f2bf(float f) {
    union { float f; unsigned u; } v; v.f = f;
    unsigned r = v.u + 0x7fffu + ((v.u >> 16) & 1u);
    return (short)(r >> 16);
}
__device__ __forceinline__ float bf2f(short s) {
    union { unsigned u; float f; } v;
    v.u = ((unsigned)(unsigned short)s) << 16;
    return v.f;
}
__device__ __forceinline__ int pack2(float a, float b) {
    return (int)(unsigned short)f2bf(a) | (((int)(unsigned short)f2bf(b)) << 16);
}

#define QSCALE 0.10206207261596575f  // 1/sqrt(96)

// ---------------------------------------------------------------------------
// Fused weight conversions (one launch).
// ---------------------------------------------------------------------------
__global__ void k_cvtall(const float* __restrict__ qw, const float* __restrict__ kw,
        const float* __restrict__ vw, const float* __restrict__ qb,
        const float* __restrict__ kb, const float* __restrict__ vb,
        const float* __restrict__ ow, const float* __restrict__ pw,
        const float* __restrict__ f1w, const float* __restrict__ f2w,
        short* __restrict__ wqkv, float* __restrict__ bqkv,
        short* __restrict__ wo16, short* __restrict__ wp16,
        short* __restrict__ wf1, short* __restrict__ wf2) {
    const int N0 = LN * 576 * 192;
    const int N1 = LN * 576;
    const int N2 = LN * HN * HN;
    const int N3 = 2 * OUTN * HN;
    const int N4 = LN * FFNN * HN * 3;
    int i = blockIdx.x * 256 + threadIdx.x;
    if (i < N0) {
        int c = i % 192, r = (i / 192) % 576, l = i / (192 * 576);
        float val, sc = 1.f;
        if (r < 192) { val = qw[((size_t)l * 192 + r) * 192 + c]; sc = QSCALE; }
        else if (r < 384) val = kw[((size_t)l * 192 + (r - 192)) * 192 + c];
        else val = vw[((size_t)l * 192 + (r - 384)) * 192 + c];
        wqkv[i] = f2bf(val * sc);
        return;
    }
    i -= N0;
    if (i < N1) {
        int r = i % 576, l = i / 576;
        bqkv[i] = (r < 192) ? qb[l * 192 + r] * QSCALE
                : (r < 384) ? kb[l * 192 + r - 192]
                            : vb[l * 192 + r - 384];
        return;
    }
    i -= N1;
    if (i < N2) { wo16[i] = f2bf(ow[i]); return; }
    i -= N2;
    if (i < N3) { wp16[i] = f2bf(pw[i]); return; }
    i -= N3;
    if (i < N4) {
        int tap = i % 3, c = (i / 3) % HN, m = (i / (3 * HN)) % FFNN, l = i / (3 * HN * FFNN);
        wf1[(((size_t)l * 3 + tap) * FFNN + m) * HN + c] = f2bf(f1w[i]);
        return;
    }
    i -= N4;
    if (i < N4) {
        int tap = i % 3, c = (i / 3) % FFNN, m = (i / (3 * FFNN)) % HN, l = i / (3 * FFNN * HN);
        wf2[(((size_t)l * 3 + tap) * HN + m) * FFNN + c] = f2bf(f2w[i]);
    }
}

// ---------------------------------------------------------------------------
// Embedding: x fp32 ch-major (B,H,T) + xb bf16 t-major (B,T,H), both masked.
// R11: 16-t tiles, grid 512 (2 blocks/CU). Verified (part of -22.9us).
// ---------------------------------------------------------------------------
__global__ __launch_bounds__(256) void k_embed(const int* __restrict__ tok,
        const int* __restrict__ lens, const float* __restrict__ emb,
        float* __restrict__ x, short* __restrict__ xb) {
    __shared__ float s[HN][17];
    const int b = blockIdx.y, t0 = blockIdx.x * 16, tid = threadIdx.x;
    const int len = lens[b];
    for (int idx = tid; idx < 16 * HN; idx += 256) {
        int tt = idx / HN, c = idx % HN;
        int t = t0 + tt;
        float v = 0.f;
        if (t < len) v = emb[tok[b * TN + t] * HN + c] * 13.856406460551018f; // sqrt(192)
        s[c][tt] = v;
    }
    __syncthreads();
    for (int idx = tid; idx < 16 * HN; idx += 256) {
        int c = idx >> 4, tt = idx & 15;
        x[((size_t)b * HN + c) * TN + t0 + tt] = s[c][tt];
    }
    for (int idx = tid; idx < 16 * 96; idx += 256) {
        int tt = idx / 96, p = idx % 96;
        ((int*)xb)[((size_t)(b * TN + t0 + tt)) * 96 + p] = pack2(s[2 * p][tt], s[2 * p + 1][tt]);
    }
}

// ---------------------------------------------------------------------------
// R12: fused o-proj + merge + residual + LN1 with W held in REGISTERS
// (18 bfrag/thread, statically determined by wave wm) -- removes the 76.8 KB
// Wt LDS buffer and its staging pass. LDS 119.5 -> ~43 KB => 2 blocks/CU
// (was the last 1-block/CU kernel). launch_bounds (512,4) caps VGPR at 128;
// budget ~115 (72 W-frags + 12 acc + transients). If spill -> revert (R2).
// ---------------------------------------------------------------------------
__global__ __launch_bounds__(512, 4) void k_oln(
        const short* __restrict__ W, const float* __restrict__ bias,
        const short* __restrict__ accP, const float* __restrict__ lPp,
        float* __restrict__ x, const float* __restrict__ g,
        const float* __restrict__ bb, short* __restrict__ xb,
        const int* __restrict__ lens) {
    __shared__ short Xt[32 * GSTR];    // 12.8 KB
    __shared__ float s_out[HN][33];    // 25.3 KB (x stage, then LN output)
    __shared__ float linv[64];
    __shared__ float red1[32 * 16], red2[32 * 16];
    __shared__ float mu[32], rs[32];
    const int b = blockIdx.y, t0 = blockIdx.x * 32;
    const int len = lens[b];
    const int tid = threadIdx.x;
    const int wave = tid >> 6, lane = tid & 63, col = lane & 15, quad = lane >> 4;
    const int wm = wave & 3, wt = wave >> 2;   // wm: m-frag group, wt: t-strip

    if (t0 >= len) {
        for (int idx = tid; idx < 32 * 96; idx += 512)
            ((int*)xb)[((size_t)(b * TN + t0 + idx / 96)) * 96 + idx % 96] = 0;
        return;
    }

    // W A-fragments direct global->register (L2-resident; quad-lanes give
    // 64B-contiguous chunks). Issued first so latency hides under staging.
    bfrag wv[3][6];
#pragma unroll
    for (int mf3 = 0; mf3 < 3; ++mf3)
#pragma unroll
        for (int ks = 0; ks < 6; ++ks)
            wv[mf3][ks] = *(const bfrag*)(
                W + ((size_t)((mf3 * 4 + wm) * 16 + col)) * 192 + ks * 32 + quad * 8);

    if (tid < 64) {
        int tt = tid & 31, h = tid >> 5;
        float l = 0.f;
#pragma unroll
        for (int sh = 0; sh < 4; ++sh)
            l += lPp[(((size_t)sh * BN + b) * NHN + h) * TN + t0 + tt];
        linv[tid] = (l > 0.f) ? 1.f / l : 0.f;
    }
    // stage x tile for residual add (hoisted: hides under merge+MFMA)
    for (int i = tid; i < 6144; i += 512) {
        int c = i >> 5, tt = i & 31;
        s_out[c][tt] = x[((size_t)b * HN + c) * TN + t0 + tt];
    }
    __syncthreads();  // linv + s_out published
    // merge accP -> Xt (32 x 24 granules), once per t
    const size_t HSq = (size_t)BN * TN * HN;
    for (int i = tid; i < 768; i += 512) {
        int tt = i / 24, part = i % 24;
        const size_t base = ((size_t)(b * TN + t0 + tt)) * 192 + part * 8;
        float a[8];
#pragma unroll
        for (int c = 0; c < 8; ++c) a[c] = 0.f;
#pragma unroll
        for (int sh = 0; sh < 4; ++sh) {
            int4 v = *(const int4*)(accP + sh * HSq + base);
            const short* sv = (const short*)&v;
#pragma unroll
            for (int c = 0; c < 8; ++c) a[c] += bf2f(sv[c]);
        }
        float li = linv[(part >= 12 ? 32 : 0) + tt];
        int4 o;
        int* oi = (int*)&o;
#pragma unroll
        for (int c = 0; c < 4; ++c) oi[c] = pack2(a[2 * c] * li, a[2 * c + 1] * li);
        *(int4*)(Xt + tt * GSTR + part * 8) = o;
    }
    __syncthreads();

    f32x4 acc[3];
#pragma unroll
    for (int mf3 = 0; mf3 < 3; ++mf3) acc[mf3] = (f32x4){0.f, 0.f, 0.f, 0.f};
#pragma unroll
    for (int ks = 0; ks < 6; ++ks) {
        bfrag bfx = *(const bfrag*)(Xt + (wt * 16 + col) * GSTR + ks * 32 + quad * 8);
#pragma unroll
        for (int mf3 = 0; mf3 < 3; ++mf3)
            acc[mf3] = __builtin_amdgcn_mfma_f32_16x16x32_bf16(wv[mf3][ks], bfx, acc[mf3], 0, 0, 0);
    }

    // residual add + per-t partial stats (each thread owns 12 channels at tcol)
    float bsv[3][4];
#pragma unroll
    for (int mf3 = 0; mf3 < 3; ++mf3)
#pragma unroll
        for (int reg = 0; reg < 4; ++reg)
            bsv[mf3][reg] = bias[(mf3 * 4 + wm) * 16 + quad * 4 + reg];
    {
        const int tcol = wt * 16 + col;
        float s1 = 0.f, s2 = 0.f;
#pragma unroll
        for (int mf3 = 0; mf3 < 3; ++mf3) {
#pragma unroll
            for (int reg = 0; reg < 4; ++reg) {
                int row = (mf3 * 4 + wm) * 16 + quad * 4 + reg;
                float v = acc[mf3][reg] + bsv[mf3][reg] + s_out[row][tcol];
                acc[mf3][reg] = v;
                s1 += v;
                s2 += v * v;
            }
        }
        red1[tcol * 16 + (wm * 4 + quad)] = s1;
        red2[tcol * 16 + (wm * 4 + quad)] = s2;
    }
    __syncthreads();
    if (tid < 32) {
        float tot = 0.f, tot2 = 0.f;
#pragma unroll
        for (int gg = 0; gg < 16; ++gg) {
            tot += red1[tid * 16 + gg];
            tot2 += red2[tid * 16 + gg];
        }
        float mean = tot / (float)HN;
        float var = tot2 / (float)HN - mean * mean;
        mu[tid] = mean;
        rs[tid] = rsqrtf(var + 1e-5f);
    }
    __syncthreads();
    // normalize into s_out (each thread writes its own 12 cells)
    {
        const int tcol = wt * 16 + col;
#pragma unroll
        for (int mf3 = 0; mf3 < 3; ++mf3) {
#pragma unroll
            for (int reg = 0; reg < 4; ++reg) {
                int row = (mf3 * 4 + wm) * 16 + quad * 4 + reg;
                s_out[row][tcol] = (acc[mf3][reg] - mu[tcol]) * rs[tcol] * g[row] + bb[row];
            }
        }
    }
    __syncthreads();
    // coalesced epilogue: x (fp32 ch-major) + xb (bf16 t-major, masked)
    for (int i = tid; i < 6144; i += 512) {
        int c = i >> 5, tt = i & 31;
        x[((size_t)b * HN + c) * TN + t0 + tt] = s_out[c][tt];
    }
    for (int idx = tid; idx < 32 * 96; idx += 512) {
        int t2 = idx / 96, p = idx % 96;
        float v0 = s_out[2 * p][t2], v1 = s_out[2 * p + 1][t2];
        if (t0 + t2 >= len) { v0 = 0.f; v1 = 0.f; }
        ((int*)xb)[((size_t)(b * TN + t0 + t2)) * 96 + p] = pack2(v0, v1);
    }
}

// ---------------------------------------------------------------------------
// R9: fused QKV projection, 128-wide t-tiles, 512 threads (8 waves: wm x wt2).
// Verified -6.7us. Masking semantics unchanged.
// ---------------------------------------------------------------------------
__global__ __launch_bounds__(512) void k_qkv2(
        const short* __restrict__ W, const short* __restrict__ X,
        const float* __restrict__ bias, short* __restrict__ qo,
        short* __restrict__ ko, short* __restrict__ vo,
        const int* __restrict__ lens) {
    __shared__ short Wt[64 * GSTR];    // 25.6 KB
    __shared__ short Xt[128 * GSTR];   // 51.2 KB
    const int b = blockIdx.z, m0 = blockIdx.y * 64, t0 = blockIdx.x * 128;
    const int len = lens[b];
    const int tid = threadIdx.x;
    const int wave = tid >> 6, lane = tid & 63, col = lane & 15, quad = lane >> 4;
    const int wm = wave & 3, wt2 = wave >> 2;  // wm: m-frag, wt2: t-half
    const int proj = m0 / 192;           // block-uniform: 0=q 1=k 2=v
    const int mbase = m0 + wm * 16 + quad * 4;
    const int mloc = mbase - proj * 192;

    if (t0 >= len) {
        if (proj == 1) return;
#pragma unroll
        for (int st = 0; st < 4; ++st) {
            int t = t0 + (wt2 * 4 + st) * 16 + col;
            if (proj == 0) {
                int2 z = {0, 0};
                *(int2*)(qo + ((size_t)(b * TN + t)) * 192 + mloc) = z;
            } else {
#pragma unroll
                for (int reg = 0; reg < 4; ++reg)
                    vo[((size_t)b * 192 + mloc + reg) * TN + t] = 0;
            }
        }
        return;
    }

    for (int i = tid; i < 1536; i += 512) {
        int mm = i / 24, part = i % 24;
        *(int4*)(Wt + mm * GSTR + part * 8) =
            *(const int4*)(W + ((size_t)(m0 + mm)) * 192 + part * 8);
    }
    for (int i = tid; i < 3072; i += 512) {
        int tt = i / 24, part = i % 24;
        *(int4*)(Xt + tt * GSTR + part * 8) =
            *(const int4*)(X + ((size_t)(b * TN + t0 + tt)) * 192 + part * 8);
    }
    __syncthreads();

    f32x4 acc[4];
#pragma unroll
    for (int st = 0; st < 4; ++st) acc[st] = (f32x4){0.f, 0.f, 0.f, 0.f};
#pragma unroll
    for (int ks = 0; ks < 6; ++ks) {
        bfrag af = *(const bfrag*)(Wt + (wm * 16 + col) * GSTR + ks * 32 + quad * 8);
#pragma unroll
        for (int st = 0; st < 4; ++st) {
            bfrag bf = *(const bfrag*)(Xt + ((wt2 * 4 + st) * 16 + col) * GSTR + ks * 32 + quad * 8);
            acc[st] = __builtin_amdgcn_mfma_f32_16x16x32_bf16(af, bf, acc[st], 0, 0, 0);
        }
    }

    float bs[4];
#pragma unroll
    for (int reg = 0; reg < 4; ++reg) bs[reg] = bias[mbase + reg];
#pragma unroll
    for (int st = 0; st < 4; ++st) {
        int t = t0 + (wt2 * 4 + st) * 16 + col;
        float v[4];
#pragma unroll
        for (int reg = 0; reg < 4; ++reg) v[reg] = acc[st][reg] + bs[reg];
        if (proj < 2) {
            short* dst = (proj == 0) ? qo : ko;
            int2 pk;
            pk.x = pack2(v[0], v[1]);
            pk.y = pack2(v[2], v[3]);
            *(int2*)(dst + ((size_t)(b * TN + t)) * 192 + mloc) = pk;
        } else {
#pragma unroll
            for (int reg = 0; reg < 4; ++reg)
                vo[((size_t)b * 192 + mloc + reg) * TN + t] = f2bf(v[reg]);
        }
    }
}

// ---------------------------------------------------------------------------
// MFMA bf16 conv (f1, f2). Masked t-tiles: zero-fill output, skip compute.
// R10: 512 threads (8 waves: wm 0..3 owns m-frag, wt2 0..1 owns t-half) --
// same grid/LDS/FLOPs, waves/CU 12->24. Verified -26.7us.
// ---------------------------------------------------------------------------
template <int TAPS, int TT, bool RELU, bool MASK_OUT, int OUTK, int KSPLIT>
__global__ __launch_bounds__(512) void k_mgemm(
        const short* __restrict__ W, const short* __restrict__ X,
        const float* __restrict__ bias, void* __restrict__ Yv,
        float* __restrict__ Yv2, float* __restrict__ Yv3,
        const int* __restrict__ lens, int M, int Cin) {
    constexpr int P = (TAPS - 1) / 2;
    constexpr int NST = TT / 16;
    constexpr int NST2 = NST / 2;      // per-wave t-frags
    __shared__ short Wt[TAPS][64][72];
    __shared__ short Xt[TT + 2 * P][72];

    const int b = blockIdx.z;
    const int mtiles = gridDim.y / KSPLIT;
    const int kg = blockIdx.y / mtiles;
    const int m0 = (blockIdx.y % mtiles) * 64;
    const int t0 = blockIdx.x * TT;
    const int len = lens[b];
    const int tid = threadIdx.x;
    const int wave = tid >> 6;
    const int lane = tid & 63;
    const int col = lane & 15;
    const int quad = lane >> 4;
    const int wm = wave & 3, wt2 = wave >> 2;  // wm: m-frag, wt2: t-half
    const int mbase = m0 + wm * 16 + quad * 4;

    if (MASK_OUT && t0 >= len) {
#pragma unroll
        for (int st = 0; st < NST2; ++st) {
            int t = t0 + (wt2 * NST2 + st) * 16 + col;
            if (OUTK == 0) {
                float* dst = (KSPLIT > 1) ? (kg == 0 ? (float*)Yv : (kg == 1 ? Yv2 : Yv3))
                                          : (float*)Yv;
#pragma unroll
                for (int reg = 0; reg < 4; ++reg)
                    dst[((size_t)b * M + mbase + reg) * TN + t] = 0.f;
            } else {
                int2 z = {0, 0};
                *(int2*)((short*)Yv + ((size_t)(b * TN + t)) * M + mbase) = z;
            }
        }
        return;
    }

    f32x4 acc[NST2];
#pragma unroll
    for (int st = 0; st < NST2; ++st) acc[st] = (f32x4){0.f, 0.f, 0.f, 0.f};

    const int cspan = Cin / KSPLIT;
    const int cbeg = kg * cspan;
    const int cend = cbeg + cspan;
    for (int c0 = cbeg; c0 < cend; c0 += 64) {
        __syncthreads();
        for (int i = tid; i < TAPS * 64 * 8; i += 512) {
            int tap = i / (64 * 8);
            int mm = (i / 8) & 63;
            int part = i & 7;
            *(int4*)(&Wt[tap][mm][part * 8]) =
                *(const int4*)(W + ((size_t)tap * M + m0 + mm) * Cin + c0 + part * 8);
        }
        for (int i = tid; i < (TT + 2 * P) * 8; i += 512) {
            int tt = i >> 3;
            int part = i & 7;
            int t = t0 + tt - P;
            int4 v = {0, 0, 0, 0};
            if (t >= 0 && t < TN)
                v = *(const int4*)(X + ((size_t)b * TN + t) * Cin + c0 + part * 8);
            *(int4*)(&Xt[tt][part * 8]) = v;
        }
        __syncthreads();
#pragma unroll
        for (int ks = 0; ks < 2; ++ks) {
#pragma unroll
            for (int tap = 0; tap < TAPS; ++tap) {
                bfrag af = *(const bfrag*)(&Wt[tap][wm * 16 + col][ks * 32 + quad * 8]);
#pragma unroll
                for (int st = 0; st < NST2; ++st) {
                    bfrag bf = *(const bfrag*)(&Xt[(wt2 * NST2 + st) * 16 + col + tap][ks * 32 + quad * 8]);
                    acc[st] = __builtin_amdgcn_mfma_f32_16x16x32_bf16(af, bf, acc[st], 0, 0, 0);
                }
            }
        }
    }

    float bs[4];
#pragma unroll
    for (int reg = 0; reg < 4; ++reg)
        bs[reg] = (KSPLIT > 1 && kg) ? 0.f : bias[mbase + reg];
#pragma unroll
    for (int st = 0; st < NST2; ++st) {
        int t = t0 + (wt2 * NST2 + st) * 16 + col;
        bool om = MASK_OUT && (t >= len);
        float v[4];
#pragma unroll
        for (int reg = 0; reg < 4; ++reg) {
            float u = acc[st][reg] + bs[reg];
            if (RELU) u = fmaxf(u, 0.f);
            if (om) u = 0.f;
            v[reg] = u;
        }
        if (OUTK == 0) {
            float* dst = (KSPLIT > 1) ? (kg == 0 ? (float*)Yv : (kg == 1 ? Yv2 : Yv3))
                                      : (float*)Yv;
#pragma unroll
            for (int reg = 0; reg < 4; ++reg)
                dst[((size_t)b * M + mbase + reg) * TN + t] = v[reg];
        } else {
            int2 pk;
            pk.x = pack2(v[0], v[1]);
            pk.y = pack2(v[2], v[3]);
            *(int2*)((short*)Yv + ((size_t)(b * TN + t)) * M + mbase) = pk;
        }
    }
}

// ---------------------------------------------------------------------------
// MFMA bf16 flash attention, partial-sum formulation.
// Masked q-tiles: write lP=0 (merge linv=0 kills stale accP) and return.
// sband stores p (not v) -> epilogue has no exp. NO register prefetch here:
// it spills under the 128-VGPR launch_bounds cap (R2: +19us).
// ---------------------------------------------------------------------------
__global__ __launch_bounds__(512, 4) void k_attn4(
        const short* __restrict__ Q, const short* __restrict__ K,
        const short* __restrict__ V, const float* __restrict__ relk,
        const float* __restrict__ relv, short* __restrict__ accP,
        float* __restrict__ lP, const int* __restrict__ lens) {
    __shared__ short kt[64 * QSTR];
    __shared__ short vt[96 * 72];
    __shared__ short Pt[128 * 72];
    __shared__ short rbt[16 * QSTR];   // relk as bf16 B-tile (rows 9..15 zero)
    __shared__ float rels[128 * 12];
    __shared__ float sband[128 * 12];  // stores p (post-mask softmax numerator)
    __shared__ float rvs[9 * 96];

    const int b = blockIdx.z;
    const int h = blockIdx.y >> 2, sh = blockIdx.y & 3;
    const int t0 = blockIdx.x * 128;
    const int len = lens[b];
    const int tid = threadIdx.x;
    const int w = tid >> 6;
    const int lane = tid & 63;
    const int col = lane & 15;
    const int quad = lane >> 4;

    if (t0 >= len) {
        if (tid < 128)
            lP[(((size_t)sh * BN + b) * NHN + h) * TN + t0 + tid] = 0.f;
        return;
    }

    const short* Qb = Q + ((size_t)b * TN + t0) * HN + h * KCN;
    const short* Kb = K + ((size_t)b * TN + sh * 256) * HN + h * KCN;
    const short* Vb = V + ((size_t)b * HN + h * KCN) * TN + sh * 256;

    bfrag qf[3];
#pragma unroll
    for (int ks = 0; ks < 3; ++ks)
        qf[ks] = *(const bfrag*)(Qb + (size_t)(w * 16 + col) * HN + ks * 32 + quad * 8);

    for (int i = tid; i < 9 * 96; i += 512) rvs[i] = relv[i];
    for (int i = tid; i < 16 * 96; i += 512) {
        int r = i / 96, c = i % 96;
        rbt[r * QSTR + c] = (r < 9) ? f2bf(relk[r * 96 + c]) : (short)0;
    }
    for (int i = tid; i < 128 * 12; i += 512) sband[i] = 0.f;
    __syncthreads();

    {
        f32x4 rc = (f32x4){0.f, 0.f, 0.f, 0.f};
#pragma unroll
        for (int ks = 0; ks < 3; ++ks) {
            bfrag bf = *(const bfrag*)(rbt + col * QSTR + ks * 32 + quad * 8);
            rc = __builtin_amdgcn_mfma_f32_16x16x32_bf16(qf[ks], bf, rc, 0, 0, 0);
        }
        if (col < 12) {
#pragma unroll
            for (int reg = 0; reg < 4; ++reg)
                rels[(w * 16 + quad * 4 + reg) * 12 + col] = rc[reg];
        }
    }

    float lsum[4];
    f32x4 accv[6];
#pragma unroll
    for (int r = 0; r < 4; ++r) lsum[r] = 0.f;
#pragma unroll
    for (int n = 0; n < 6; ++n) accv[n] = (f32x4){0.f, 0.f, 0.f, 0.f};

    const int rem = len - sh * 256;
    const int nj = (rem <= 0) ? 0 : ((rem >= 256) ? 4 : ((rem + 63) >> 6));

    for (int j = 0; j < nj; ++j) {
        const int s0g = sh * 256 + j * 64;
        __syncthreads();
        for (int i = tid; i < 768; i += 512) {
            int row = i / 12, part = i % 12;
            *(int4*)(kt + row * QSTR + part * 8) =
                *(const int4*)(Kb + ((size_t)(j * 64 + row)) * HN + part * 8);
        }
        for (int i = tid; i < 768; i += 512) {
            int c = i >> 3, part = i & 7;
            *(int4*)(vt + c * 72 + part * 8) =
                *(const int4*)(Vb + (size_t)c * TN + j * 64 + part * 8);
        }
        __syncthreads();

        f32x4 sacc[4];
#pragma unroll
        for (int st = 0; st < 4; ++st) sacc[st] = (f32x4){0.f, 0.f, 0.f, 0.f};
#pragma unroll
        for (int ks = 0; ks < 3; ++ks) {
#pragma unroll
            for (int st = 0; st < 4; ++st) {
                bfrag bf = *(const bfrag*)(kt + (st * 16 + col) * QSTR + ks * 32 + quad * 8);
                sacc[st] = __builtin_amdgcn_mfma_f32_16x16x32_bf16(qf[ks], bf, sacc[st], 0, 0, 0);
            }
        }

#pragma unroll
        for (int reg = 0; reg < 4; ++reg) {
            const int lq = w * 16 + quad * 4 + reg;
            const int qg = t0 + lq;
#pragma unroll
            for (int st = 0; st < 4; ++st) {
                int sg = s0g + st * 16 + col;
                float v = sacc[st][reg];
                int d = sg - qg + 4;
                bool inb = (d >= 0) && (d <= 8);
                if (inb) v += rels[lq * 12 + d];
                if (sg >= len) v = -1e4f;
                float p = __expf(v - M0S);
                if (inb) sband[lq * 12 + d] = p;
                lsum[reg] += p;
                Pt[lq * 72 + st * 16 + col] = f2bf(p);
            }
        }
#pragma unroll
        for (int ks = 0; ks < 2; ++ks) {
            bfrag af = *(const bfrag*)(Pt + (w * 16 + col) * 72 + ks * 32 + quad * 8);
#pragma unroll
            for (int nt = 0; nt < 6; ++nt) {
                bfrag bf = *(const bfrag*)(vt + (nt * 16 + col) * 72 + ks * 32 + quad * 8);
                accv[nt] = __builtin_amdgcn_mfma_f32_16x16x32_bf16(af, bf, accv[nt], 0, 0, 0);
            }
        }
    }

#pragma unroll
    for (int reg = 0; reg < 4; ++reg) {
        lsum[reg] += __shfl_xor(lsum[reg], 1);
        lsum[reg] += __shfl_xor(lsum[reg], 2);
        lsum[reg] += __shfl_xor(lsum[reg], 4);
        lsum[reg] += __shfl_xor(lsum[reg], 8);
    }
    __syncthreads();

    short* aout = accP + (size_t)sh * BN * TN * HN;
#pragma unroll
    for (int reg = 0; reg < 4; ++reg) {
        const int lq = w * 16 + quad * 4 + reg;
        const int qg = t0 + lq;
        float pb[9];
#pragma unroll
        for (int d = 0; d < 9; ++d)
            pb[d] = sband[lq * 12 + d];
#pragma unroll
        for (int nt = 0; nt < 6; ++nt) {
            int c = nt * 16 + col;
            float r = accv[nt][reg];
#pragma unroll
            for (int d = 0; d < 9; ++d) r += pb[d] * rvs[d * 96 + c];
            aout[((size_t)(b * TN + qg)) * HN + h * KCN + c] = f2bf(r);
        }
        if (col == 0)
            lP[(((size_t)sh * BN + b) * NHN + h) * TN + qg] = lsum[reg];
    }
}

// ---------------------------------------------------------------------------
// Residual + LayerNorm: x = LN(x + y [+ y2 [+ y3]])*g + b, fp32 in-place;
// masked bf16 t-major copy xb. Fully-masked tiles: zero xb only (x is dead).
// R8: 512 threads + float4 loads/stores + int2 xb writes. Verified -11.5us.
// ---------------------------------------------------------------------------
template <int NADD>
__global__ __launch_bounds__(512) void k_ln(float* __restrict__ x,
        const float* __restrict__ y, const float* __restrict__ y2,
        const float* __restrict__ y3, const float* __restrict__ g,
        const float* __restrict__ bb, short* __restrict__ xb,
        const int* __restrict__ lens) {
    __shared__ float s[HN][33];
    __shared__ float red1[512], red2[512];
    __shared__ float mu[32], rs[32];
    const int b = blockIdx.y;
    const int t0 = blockIdx.x * 32;
    const int tid = threadIdx.x;
    const int len = lens[b];

    if (t0 >= len) {
        for (int i = tid; i < 32 * 48; i += 512) {
            int2 z = {0, 0};
            *(int2*)((int*)xb + ((size_t)(b * TN + t0 + i / 48)) * 96 + (i % 48) * 2) = z;
        }
        return;
    }

    // vectorized gather: 192 ch x 8 float4-groups = 1536 items, 3 per thread
    for (int i = tid; i < HN * 8; i += 512) {
        int c = i >> 3, tq = i & 7;
        size_t gi = ((size_t)b * HN + c) * TN + t0 + tq * 4;
        float4 v = *(const float4*)(x + gi);
        float4 a = *(const float4*)(y + gi);
        v.x += a.x; v.y += a.y; v.z += a.z; v.w += a.w;
        if (NADD >= 2) {
            float4 a2 = *(const float4*)(y2 + gi);
            v.x += a2.x; v.y += a2.y; v.z += a2.z; v.w += a2.w;
        }
        if (NADD >= 3) {
            float4 a3 = *(const float4*)(y3 + gi);
            v.x += a3.x; v.y += a3.y; v.z += a3.z; v.w += a3.w;
        }
        s[c][tq * 4 + 0] = v.x;
        s[c][tq * 4 + 1] = v.y;
        s[c][tq * 4 + 2] = v.z;
        s[c][tq * 4 + 3] = v.w;
    }
    __syncthreads();
    int tt = tid & 31, grp = tid >> 5;  // 16 groups x 12 channels
    float sum = 0.f, sum2 = 0.f;
    for (int c = grp * 12; c < grp * 12 + 12; ++c) {
        float v = s[c][tt];
        sum += v;
        sum2 += v * v;
    }
    red1[tid] = sum;
    red2[tid] = sum2;
    __syncthreads();
    if (tid < 32) {
        float tot = 0.f, tot2 = 0.f;
#pragma unroll
        for (int gg = 0; gg < 16; ++gg) { tot += red1[gg * 32 + tid]; tot2 += red2[gg * 32 + tid]; }
        float mean = tot / (float)HN;
        float var = tot2 / (float)HN - mean * mean;
        mu[tid] = mean;
        rs[tid] = rsqrtf(var + 1e-5f);
    }
    __syncthreads();
    // normalized x (fp32 ch-major, float4)
    for (int i = tid; i < HN * 8; i += 512) {
        int c = i >> 3, tq = i & 7;
        float gc = g[c], bc = bb[c];
        float4 o;
        o.x = (s[c][tq * 4 + 0] - mu[tq * 4 + 0]) * rs[tq * 4 + 0] * gc + bc;
        o.y = (s[c][tq * 4 + 1] - mu[tq * 4 + 1]) * rs[tq * 4 + 1] * gc + bc;
        o.z = (s[c][tq * 4 + 2] - mu[tq * 4 + 2]) * rs[tq * 4 + 2] * gc + bc;
        o.w = (s[c][tq * 4 + 3] - mu[tq * 4 + 3]) * rs[tq * 4 + 3] * gc + bc;
        *(float4*)(x + ((size_t)b * HN + c) * TN + t0 + tq * 4) = o;
    }
    // xb bf16 t-major, int2-packed (4 channels per item), masked
    for (int i = tid; i < 32 * 48; i += 512) {
        int t2 = i / 48, p2 = i % 48;
        int c0 = p2 * 4;
        float m = mu[t2], r = rs[t2];
        float v0 = (s[c0][t2] - m) * r * g[c0] + bb[c0];
        float v1 = (s[c0 + 1][t2] - m) * r * g[c0 + 1] + bb[c0 + 1];
        float v2 = (s[c0 + 2][t2] - m) * r * g[c0 + 2] + bb[c0 + 2];
        float v3 = (s[c0 + 3][t2] - m) * r * g[c0 + 3] + bb[c0 + 3];
        if (t0 + t2 >= len) { v0 = 0.f; v1 = 0.f; v2 = 0.f; v3 = 0.f; }
        int2 pk;
        pk.x = pack2(v0, v1);
        pk.y = pack2(v2, v3);
        *(int2*)((int*)xb + ((size_t)(b * TN + t0 + t2)) * 96 + p2 * 2) = pk;
    }
}

// ---------------------------------------------------------------------------
// Fused stats projection + final sampling.
// R11: 512 threads (wm x wt2 wave split). Verified (part of -22.9us).
// ---------------------------------------------------------------------------
__global__ __launch_bounds__(512) void k_statsfin(
        const short* __restrict__ W, const short* __restrict__ X,
        const float* __restrict__ bias, const float* __restrict__ x,
        const float* __restrict__ eps, const int* __restrict__ lens,
        float* __restrict__ out) {
    __shared__ short Wt[64 * GSTR];
    __shared__ short Xt[64 * GSTR];
    const int b = blockIdx.z, o0 = blockIdx.y * 64, t0 = blockIdx.x * 64;
    const int len = lens[b];
    const int tid = threadIdx.x;
    const int wave = tid >> 6, lane = tid & 63, col = lane & 15, quad = lane >> 4;
    const int wm = wave & 3, wt2 = wave >> 2;  // wm: o-frag, wt2: t-half
    const size_t S = (size_t)BN * OUTN * TN;

    if (t0 >= len) {
        for (int i = tid; i < 4096; i += 512) {
            int oo = i >> 6, tt = i & 63;
            size_t idx = ((size_t)b * OUTN + o0 + oo) * TN + t0 + tt;
            out[idx] = 0.f;
            out[S + idx] = 0.f;
            out[2 * S + idx] = 0.f;
            out[3 * S + idx] = 0.f;
        }
        if (o0 == 0 && tid < 64) out[4 * S + (size_t)b * TN + t0 + tid] = 0.f;
        return;
    }

    for (int i = tid; i < 1536; i += 512) {
        int tt = i / 24, part = i % 24;
        *(int4*)(Xt + tt * GSTR + part * 8) =
            *(const int4*)(X + ((size_t)(b * TN + t0 + tt)) * 192 + part * 8);
    }
    for (int i = tid; i < 1536; i += 512) {
        int mm = i / 24, part = i % 24;
        *(int4*)(Wt + mm * GSTR + part * 8) =
            *(const int4*)(W + ((size_t)(o0 + mm)) * 192 + part * 8);
    }
    __syncthreads();

    f32x4 am[2];
#pragma unroll
    for (int st = 0; st < 2; ++st) am[st] = (f32x4){0.f, 0.f, 0.f, 0.f};
#pragma unroll
    for (int ks = 0; ks < 6; ++ks) {
        bfrag af = *(const bfrag*)(Wt + (wm * 16 + col) * GSTR + ks * 32 + quad * 8);
#pragma unroll
        for (int st = 0; st < 2; ++st) {
            bfrag bf = *(const bfrag*)(Xt + ((wt2 * 2 + st) * 16 + col) * GSTR + ks * 32 + quad * 8);
            am[st] = __builtin_amdgcn_mfma_f32_16x16x32_bf16(af, bf, am[st], 0, 0, 0);
        }
    }
    __syncthreads();
    for (int i = tid; i < 1536; i += 512) {
        int mm = i / 24, part = i % 24;
        *(int4*)(Wt + mm * GSTR + part * 8) =
            *(const int4*)(W + ((size_t)(192 + o0 + mm)) * 192 + part * 8);
    }
    __syncthreads();

    f32x4 al[2];
#pragma unroll
    for (int st = 0; st < 2; ++st) al[st] = (f32x4){0.f, 0.f, 0.f, 0.f};
#pragma unroll
    for (int ks = 0; ks < 6; ++ks) {
        bfrag af = *(const bfrag*)(Wt + (wm * 16 + col) * GSTR + ks * 32 + quad * 8);
#pragma unroll
        for (int st = 0; st < 2; ++st) {
            bfrag bf = *(const bfrag*)(Xt + ((wt2 * 2 + st) * 16 + col) * GSTR + ks * 32 + quad * 8);
            al[st] = __builtin_amdgcn_mfma_f32_16x16x32_bf16(af, bf, al[st], 0, 0, 0);
        }
    }

    const int obase = o0 + wm * 16 + quad * 4;
    float bm[4], bl[4];
#pragma unroll
    for (int reg = 0; reg < 4; ++reg) {
        bm[reg] = bias[obase + reg];
        bl[reg] = bias[192 + obase + reg];
    }
#pragma unroll
    for (int st = 0; st < 2; ++st) {
        int t = t0 + (wt2 * 2 + st) * 16 + col;
        bool om = (t >= len);
#pragma unroll
        for (int reg = 0; reg < 4; ++reg) {
            float m = am[st][reg] + bm[reg];
            float ls = al[st][reg] + bl[reg];
            if (om) { m = 0.f; ls = 0.f; }
            size_t idx = ((size_t)b * OUTN + obase + reg) * TN + t;
            float e = eps[idx];
            out[idx] = om ? 0.f : m + e * __expf(ls);
            out[S + idx] = m;
            out[2 * S + idx] = ls;
        }
    }
    for (int i = tid; i < 4096; i += 512) {
        int oo = i >> 6, tt = i & 63;
        int t = t0 + tt;
        float mv = (t < len) ? 1.f : 0.f;
        size_t idx = ((size_t)b * OUTN + o0 + oo) * TN + t;
        out[3 * S + idx] = x[((size_t)b * HN + o0 + oo) * TN + t] * mv;
    }
    if (o0 == 0 && tid < 64)
        out[4 * S + (size_t)b * TN + t0 + tid] = (t0 + tid < len) ? 1.f : 0.f;
}

// ---------------------------------------------------------------------------
extern "C" void kernel_launch(void* const* d_in, const int* in_sizes, int n_in,
                              void* d_out, int out_size, void* d_ws, size_t ws_size,
                              hipStream_t stream) {
    const int* tok = (const int*)d_in[0];
    const int* lens = (const int*)d_in[1];
    const float* emb = (const float*)d_in[2];
    const float* qw = (const float*)d_in[3];
    const float* qb = (const float*)d_in[4];
    const float* kw = (const float*)d_in[5];
    const float* kb = (const float*)d_in[6];
    const float* vw = (const float*)d_in[7];
    const float* vb = (const float*)d_in[8];
    const float* ow = (const float*)d_in[9];
    const float* ob = (const float*)d_in[10];
    const float* relk = (const float*)d_in[11];
    const float* relv = (const float*)d_in[12];
    const float* ln1g = (const float*)d_in[13];
    const float* ln1b = (const float*)d_in[14];
    const float* f1w = (const float*)d_in[15];
    const float* f1b = (const float*)d_in[16];
    const float* f2w = (const float*)d_in[17];
    const float* f2b = (const float*)d_in[18];
    const float* ln2g = (const float*)d_in[19];
    const float* ln2b = (const float*)d_in[20];
    const float* pw = (const float*)d_in[21];
    const float* pb = (const float*)d_in[22];
    const float* eps = (const float*)d_in[23];

    const size_t BHT = (size_t)BN * HN * TN; // 1,572,864
    float* ws = (float*)d_ws;
    float* x = ws;                                   // fp32 ch-major
    float* yf = ws + BHT;                            // fp32 ch-major (f2 kg=0)
    short* s_xb = (short*)(ws + 2 * BHT);            // bf16 t-major (qkv/stats in)
    short* s_ln = (short*)(ws + 2 * BHT + BHT / 2);  // bf16 t-major (f1 in)
    short* s_q  = (short*)(ws + 3 * BHT);
    short* s_k  = (short*)(ws + 3 * BHT + BHT / 2);
    short* s_v  = (short*)(ws + 4 * BHT);
    float* p1   = ws + 3 * BHT;   // f2 partial kg=1 (overlays s_q/s_k: dead by then)
    float* p2   = ws + 4 * BHT;   // f2 partial kg=2 (overlays s_v + free slot)
    short* accP = (short*)(ws + 5 * BHT);            // 4 x BHT shorts (attn partials)
    short* s_y1 = (short*)(ws + 5 * BHT);            // f1 out (B,T,FFN), after attn consumed
    short* wqkv = (short*)(ws + 7 * BHT);            // [L][576][192]
    short* wo16 = wqkv + (size_t)LN * 3 * HN * HN;
    short* wp16 = wo16 + (size_t)LN * HN * HN;
    short* wf1_16 = wp16 + (size_t)2 * OUTN * HN;
    short* wf2_16 = wf1_16 + (size_t)LN * 3 * FFNN * HN;
    float* bqkv = (float*)(wf2_16 + (size_t)LN * 3 * FFNN * HN);  // [L][576]
    float* lP = bqkv + (size_t)LN * 576;             // 4 x B x NH x T floats

    // fused weight conversion (single launch)
    {
        long total = (long)LN * 576 * 192 + LN * 576 + LN * HN * HN + 2 * OUTN * HN
                   + 2L * LN * FFNN * HN * 3;
        k_cvtall<<<dim3((unsigned)((total + 255) / 256)), 256, 0, stream>>>(
            qw, kw, vw, qb, kb, vb, ow, pw, f1w, f2w,
            wqkv, bqkv, wo16, wp16, wf1_16, wf2_16);
    }

    dim3 gemb(TN / 16, BN);             // 64 x 8 (2 blocks/CU for token gather)
    k_embed<<<gemb, 256, 0, stream>>>(tok, lens, emb, x, s_xb);

    dim3 gqkv(TN / 128, 9, BN);         // 8 x 9 x 8 (512 thr)
    dim3 gattn(TN / 128, NHN * 4, BN);  // 8 x 8 x 8 (512-thread blocks)
    dim3 gol(TN / 32, BN);              // 32 x 8 (oln, W-in-regs, 2 blocks/CU)
    dim3 gf1(TN / 128, FFNN / 64, BN);  // 8 x 12 x 8 (512 thr)
    dim3 gf2(TN / 128, 9, BN);          // 8 x (3m x 3kg) x 8 (512 thr)
    dim3 gln(TN / 32, BN);              // 32 x 8 (512 thr)

    for (int i = 0; i < LN; ++i) {
        const short* qkvwi = wqkv + (size_t)i * 576 * 192;
        const float* qkvbi = bqkv + (size_t)i * 576;
        const short* owi = wo16 + (size_t)i * HN * HN;
        const short* f1wi = wf1_16 + (size_t)i * 3 * FFNN * HN;
        const short* f2wi = wf2_16 + (size_t)i * 3 * FFNN * HN;
        const float* obi = ob + (size_t)i * HN;
        const float* rki = relk + (size_t)i * 9 * KCN;
        const float* rvi = relv + (size_t)i * 9 * KCN;
        const float* l1gi = ln1g + (size_t)i * HN;
        const float* l1bi = ln1b + (size_t)i * HN;
        const float* f1bi = f1b + (size_t)i * FFNN;
        const float* f2bi = f2b + (size_t)i * HN;
        const float* l2gi = ln2g + (size_t)i * HN;
        const float* l2bi = ln2b + (size_t)i * HN;

        k_qkv2<<<gqkv, 512, 0, stream>>>(qkvwi, s_xb, qkvbi, s_q, s_k, s_v, lens);
        k_attn4<<<gattn, 512, 0, stream>>>(s_q, s_k, s_v, rki, rvi, accP, lP, lens);
        k_oln<<<gol, 512, 0, stream>>>(owi, obi, accP, lP, x, l1gi, l1bi, s_ln, lens);
        k_mgemm<3, 128, true, true, 1, 1><<<gf1, 512, 0, stream>>>(f1wi, s_ln, f1bi, s_y1, nullptr, nullptr, lens, FFNN, HN);
        k_mgemm<3, 128, false, true, 0, 3><<<gf2, 512, 0, stream>>>(f2wi, s_y1, f2bi, yf, p1, p2, lens, HN, FFNN);
        k_ln<3><<<gln, 512, 0, stream>>>(x, yf, p1, p2, l2gi, l2bi, s_xb, lens);
    }

    dim3 gsf(TN / 64, OUTN / 64, BN);   // 16 x 3 x 8 (512 thr)
    k_statsfin<<<gsf, 512, 0, stream>>>(wp16, s_xb, pb, x, eps, lens, (float*)d_out);
}

// Round 14
// 760.385 us; speedup vs baseline: 1.0109x; 1.0109x over previous
//
#include <hip/hip_runtime.h>
#include <math.h>

#define BN 8
#define TN 1024
#define HN 192
#define NHN 2
#define KCN 96
#define LN 6
#define FFNN 768
#define OUTN 192
#define QSTR 104  // kt/rbt LDS row stride in shorts: 13 granules (odd) -> conflict-free b128
#define GSTR 200  // K=192 GEMM LDS row stride (192 data + pad): 25 granules (odd)
#define M0S 12.0f // fixed softmax shift: scores are O(1); exp(s-12) safe to s~100

typedef short bfrag __attribute__((ext_vector_type(8)));
typedef float f32x4 __attribute__((ext_vector_type(4)));

__device__ __forceinline__ short f2bf(float f) {
    union { float f; unsigned u; } v; v.f = f;
    unsigned r = v.u + 0x7fffu + ((v.u >> 16) & 1u);
    return (short)(r >> 16);
}
__device__ __forceinline__ float bf2f(short s) {
    union { unsigned u; float f; } v;
    v.u = ((unsigned)(unsigned short)s) << 16;
    return v.f;
}
__device__ __forceinline__ int pack2(float a, float b) {
    return (int)(unsigned short)f2bf(a) | (((int)(unsigned short)f2bf(b)) << 16);
}

#define QSCALE 0.10206207261596575f  // 1/sqrt(96)

// ---------------------------------------------------------------------------
// Fused weight conversions (one launch).
// ---------------------------------------------------------------------------
__global__ void k_cvtall(const float* __restrict__ qw, const float* __restrict__ kw,
        const float* __restrict__ vw, const float* __restrict__ qb,
        const float* __restrict__ kb, const float* __restrict__ vb,
        const float* __restrict__ ow, const float* __restrict__ pw,
        const float* __restrict__ f1w, const float* __restrict__ f2w,
        short* __restrict__ wqkv, float* __restrict__ bqkv,
        short* __restrict__ wo16, short* __restrict__ wp16,
        short* __restrict__ wf1, short* __restrict__ wf2) {
    const int N0 = LN * 576 * 192;
    const int N1 = LN * 576;
    const int N2 = LN * HN * HN;
    const int N3 = 2 * OUTN * HN;
    const int N4 = LN * FFNN * HN * 3;
    int i = blockIdx.x * 256 + threadIdx.x;
    if (i < N0) {
        int c = i % 192, r = (i / 192) % 576, l = i / (192 * 576);
        float val, sc = 1.f;
        if (r < 192) { val = qw[((size_t)l * 192 + r) * 192 + c]; sc = QSCALE; }
        else if (r < 384) val = kw[((size_t)l * 192 + (r - 192)) * 192 + c];
        else val = vw[((size_t)l * 192 + (r - 384)) * 192 + c];
        wqkv[i] = f2bf(val * sc);
        return;
    }
    i -= N0;
    if (i < N1) {
        int r = i % 576, l = i / 576;
        bqkv[i] = (r < 192) ? qb[l * 192 + r] * QSCALE
                : (r < 384) ? kb[l * 192 + r - 192]
                            : vb[l * 192 + r - 384];
        return;
    }
    i -= N1;
    if (i < N2) { wo16[i] = f2bf(ow[i]); return; }
    i -= N2;
    if (i < N3) { wp16[i] = f2bf(pw[i]); return; }
    i -= N3;
    if (i < N4) {
        int tap = i % 3, c = (i / 3) % HN, m = (i / (3 * HN)) % FFNN, l = i / (3 * HN * FFNN);
        wf1[(((size_t)l * 3 + tap) * FFNN + m) * HN + c] = f2bf(f1w[i]);
        return;
    }
    i -= N4;
    if (i < N4) {
        int tap = i % 3, c = (i / 3) % FFNN, m = (i / (3 * FFNN)) % HN, l = i / (3 * FFNN * HN);
        wf2[(((size_t)l * 3 + tap) * HN + m) * FFNN + c] = f2bf(f2w[i]);
    }
}

// ---------------------------------------------------------------------------
// Embedding: x fp32 ch-major (B,H,T) + xb bf16 t-major (B,T,H), both masked.
// R11: 16-t tiles, grid 512 (2 blocks/CU). Verified (part of -22.9us).
// ---------------------------------------------------------------------------
__global__ __launch_bounds__(256) void k_embed(const int* __restrict__ tok,
        const int* __restrict__ lens, const float* __restrict__ emb,
        float* __restrict__ x, short* __restrict__ xb) {
    __shared__ float s[HN][17];
    const int b = blockIdx.y, t0 = blockIdx.x * 16, tid = threadIdx.x;
    const int len = lens[b];
    for (int idx = tid; idx < 16 * HN; idx += 256) {
        int tt = idx / HN, c = idx % HN;
        int t = t0 + tt;
        float v = 0.f;
        if (t < len) v = emb[tok[b * TN + t] * HN + c] * 13.856406460551018f; // sqrt(192)
        s[c][tt] = v;
    }
    __syncthreads();
    for (int idx = tid; idx < 16 * HN; idx += 256) {
        int c = idx >> 4, tt = idx & 15;
        x[((size_t)b * HN + c) * TN + t0 + tt] = s[c][tt];
    }
    for (int idx = tid; idx < 16 * 96; idx += 256) {
        int tt = idx / 96, p = idx % 96;
        ((int*)xb)[((size_t)(b * TN + t0 + tt)) * 96 + p] = pack2(s[2 * p][tt], s[2 * p + 1][tt]);
    }
}

// ---------------------------------------------------------------------------
// R13 = R11 k_oln (REVERT of R12's W-in-registers: fractured 384B-stride
// global loads + 72 live VGPRs under the 128-cap cost +6.7us. Lesson: wave
// splits win; register-resident staged data under tight caps loses.)
// Fused o-proj + merge + residual + LN1, 512 threads (wm x wt), LDS-staged W,
// hoisted x residual staging. Verified 761.9us total.
// ---------------------------------------------------------------------------
__global__ __launch_bounds__(512, 2) void k_oln(
        const short* __restrict__ W, const float* __restrict__ bias,
        const short* __restrict__ accP, const float* __restrict__ lPp,
        float* __restrict__ x, const float* __restrict__ g,
        const float* __restrict__ bb, short* __restrict__ xb,
        const int* __restrict__ lens) {
    __shared__ short Wt[192 * GSTR];   // 76.8 KB
    __shared__ short Xt[32 * GSTR];    // 12.8 KB
    __shared__ float s_out[HN][33];    // 25.3 KB (x stage, then LN output)
    __shared__ float linv[64];
    __shared__ float red1[32 * 16], red2[32 * 16];
    __shared__ float mu[32], rs[32];
    const int b = blockIdx.y, t0 = blockIdx.x * 32;
    const int len = lens[b];
    const int tid = threadIdx.x;
    const int wave = tid >> 6, lane = tid & 63, col = lane & 15, quad = lane >> 4;
    const int wm = wave & 3, wt = wave >> 2;   // wm: m-frag group, wt: t-strip

    if (t0 >= len) {
        for (int idx = tid; idx < 32 * 96; idx += 512)
            ((int*)xb)[((size_t)(b * TN + t0 + idx / 96)) * 96 + idx % 96] = 0;
        return;
    }

    if (tid < 64) {
        int tt = tid & 31, h = tid >> 5;
        float l = 0.f;
#pragma unroll
        for (int sh = 0; sh < 4; ++sh)
            l += lPp[(((size_t)sh * BN + b) * NHN + h) * TN + t0 + tt];
        linv[tid] = (l > 0.f) ? 1.f / l : 0.f;
    }
    // stage W (192 x 24 granules)
    for (int i = tid; i < 4608; i += 512) {
        int mm = i / 24, part = i % 24;
        *(int4*)(Wt + mm * GSTR + part * 8) =
            *(const int4*)(W + ((size_t)mm) * 192 + part * 8);
    }
    // stage x tile for residual add (hoisted: hides under merge+MFMA)
    for (int i = tid; i < 6144; i += 512) {
        int c = i >> 5, tt = i & 31;
        s_out[c][tt] = x[((size_t)b * HN + c) * TN + t0 + tt];
    }
    __syncthreads();  // linv ready for merge; W/s_out published
    // merge accP -> Xt (32 x 24 granules), once per t
    const size_t HSq = (size_t)BN * TN * HN;
    for (int i = tid; i < 768; i += 512) {
        int tt = i / 24, part = i % 24;
        const size_t base = ((size_t)(b * TN + t0 + tt)) * 192 + part * 8;
        float a[8];
#pragma unroll
        for (int c = 0; c < 8; ++c) a[c] = 0.f;
#pragma unroll
        for (int sh = 0; sh < 4; ++sh) {
            int4 v = *(const int4*)(accP + sh * HSq + base);
            const short* sv = (const short*)&v;
#pragma unroll
            for (int c = 0; c < 8; ++c) a[c] += bf2f(sv[c]);
        }
        float li = linv[(part >= 12 ? 32 : 0) + tt];
        int4 o;
        int* oi = (int*)&o;
#pragma unroll
        for (int c = 0; c < 4; ++c) oi[c] = pack2(a[2 * c] * li, a[2 * c + 1] * li);
        *(int4*)(Xt + tt * GSTR + part * 8) = o;
    }
    __syncthreads();

    f32x4 acc[3];
#pragma unroll
    for (int mf3 = 0; mf3 < 3; ++mf3) acc[mf3] = (f32x4){0.f, 0.f, 0.f, 0.f};
#pragma unroll
    for (int ks = 0; ks < 6; ++ks) {
        bfrag bfx = *(const bfrag*)(Xt + (wt * 16 + col) * GSTR + ks * 32 + quad * 8);
#pragma unroll
        for (int mf3 = 0; mf3 < 3; ++mf3) {
            int mf = mf3 * 4 + wm;
            bfrag af = *(const bfrag*)(Wt + (mf * 16 + col) * GSTR + ks * 32 + quad * 8);
            acc[mf3] = __builtin_amdgcn_mfma_f32_16x16x32_bf16(af, bfx, acc[mf3], 0, 0, 0);
        }
    }

    // residual add + per-t partial stats (each thread owns 12 channels at tcol)
    float bsv[3][4];
#pragma unroll
    for (int mf3 = 0; mf3 < 3; ++mf3)
#pragma unroll
        for (int reg = 0; reg < 4; ++reg)
            bsv[mf3][reg] = bias[(mf3 * 4 + wm) * 16 + quad * 4 + reg];
    {
        const int tcol = wt * 16 + col;
        float s1 = 0.f, s2 = 0.f;
#pragma unroll
        for (int mf3 = 0; mf3 < 3; ++mf3) {
#pragma unroll
            for (int reg = 0; reg < 4; ++reg) {
                int row = (mf3 * 4 + wm) * 16 + quad * 4 + reg;
                float v = acc[mf3][reg] + bsv[mf3][reg] + s_out[row][tcol];
                acc[mf3][reg] = v;
                s1 += v;
                s2 += v * v;
            }
        }
        red1[tcol * 16 + (wm * 4 + quad)] = s1;
        red2[tcol * 16 + (wm * 4 + quad)] = s2;
    }
    __syncthreads();
    if (tid < 32) {
        float tot = 0.f, tot2 = 0.f;
#pragma unroll
        for (int gg = 0; gg < 16; ++gg) {
            tot += red1[tid * 16 + gg];
            tot2 += red2[tid * 16 + gg];
        }
        float mean = tot / (float)HN;
        float var = tot2 / (float)HN - mean * mean;
        mu[tid] = mean;
        rs[tid] = rsqrtf(var + 1e-5f);
    }
    __syncthreads();
    // normalize into s_out (each thread writes its own 12 cells)
    {
        const int tcol = wt * 16 + col;
#pragma unroll
        for (int mf3 = 0; mf3 < 3; ++mf3) {
#pragma unroll
            for (int reg = 0; reg < 4; ++reg) {
                int row = (mf3 * 4 + wm) * 16 + quad * 4 + reg;
                s_out[row][tcol] = (acc[mf3][reg] - mu[tcol]) * rs[tcol] * g[row] + bb[row];
            }
        }
    }
    __syncthreads();
    // coalesced epilogue: x (fp32 ch-major) + xb (bf16 t-major, masked)
    for (int i = tid; i < 6144; i += 512) {
        int c = i >> 5, tt = i & 31;
        x[((size_t)b * HN + c) * TN + t0 + tt] = s_out[c][tt];
    }
    for (int idx = tid; idx < 32 * 96; idx += 512) {
        int t2 = idx / 96, p = idx % 96;
        float v0 = s_out[2 * p][t2], v1 = s_out[2 * p + 1][t2];
        if (t0 + t2 >= len) { v0 = 0.f; v1 = 0.f; }
        ((int*)xb)[((size_t)(b * TN + t0 + t2)) * 96 + p] = pack2(v0, v1);
    }
}

// ---------------------------------------------------------------------------
// R9: fused QKV projection, 128-wide t-tiles, 512 threads (8 waves: wm x wt2).
// Verified -6.7us. Masking semantics unchanged.
// ---------------------------------------------------------------------------
__global__ __launch_bounds__(512) void k_qkv2(
        const short* __restrict__ W, const short* __restrict__ X,
        const float* __restrict__ bias, short* __restrict__ qo,
        short* __restrict__ ko, short* __restrict__ vo,
        const int* __restrict__ lens) {
    __shared__ short Wt[64 * GSTR];    // 25.6 KB
    __shared__ short Xt[128 * GSTR];   // 51.2 KB
    const int b = blockIdx.z, m0 = blockIdx.y * 64, t0 = blockIdx.x * 128;
    const int len = lens[b];
    const int tid = threadIdx.x;
    const int wave = tid >> 6, lane = tid & 63, col = lane & 15, quad = lane >> 4;
    const int wm = wave & 3, wt2 = wave >> 2;  // wm: m-frag, wt2: t-half
    const int proj = m0 / 192;           // block-uniform: 0=q 1=k 2=v
    const int mbase = m0 + wm * 16 + quad * 4;
    const int mloc = mbase - proj * 192;

    if (t0 >= len) {
        if (proj == 1) return;
#pragma unroll
        for (int st = 0; st < 4; ++st) {
            int t = t0 + (wt2 * 4 + st) * 16 + col;
            if (proj == 0) {
                int2 z = {0, 0};
                *(int2*)(qo + ((size_t)(b * TN + t)) * 192 + mloc) = z;
            } else {
#pragma unroll
                for (int reg = 0; reg < 4; ++reg)
                    vo[((size_t)b * 192 + mloc + reg) * TN + t] = 0;
            }
        }
        return;
    }

    for (int i = tid; i < 1536; i += 512) {
        int mm = i / 24, part = i % 24;
        *(int4*)(Wt + mm * GSTR + part * 8) =
            *(const int4*)(W + ((size_t)(m0 + mm)) * 192 + part * 8);
    }
    for (int i = tid; i < 3072; i += 512) {
        int tt = i / 24, part = i % 24;
        *(int4*)(Xt + tt * GSTR + part * 8) =
            *(const int4*)(X + ((size_t)(b * TN + t0 + tt)) * 192 + part * 8);
    }
    __syncthreads();

    f32x4 acc[4];
#pragma unroll
    for (int st = 0; st < 4; ++st) acc[st] = (f32x4){0.f, 0.f, 0.f, 0.f};
#pragma unroll
    for (int ks = 0; ks < 6; ++ks) {
        bfrag af = *(const bfrag*)(Wt + (wm * 16 + col) * GSTR + ks * 32 + quad * 8);
#pragma unroll
        for (int st = 0; st < 4; ++st) {
            bfrag bf = *(const bfrag*)(Xt + ((wt2 * 4 + st) * 16 + col) * GSTR + ks * 32 + quad * 8);
            acc[st] = __builtin_amdgcn_mfma_f32_16x16x32_bf16(af, bf, acc[st], 0, 0, 0);
        }
    }

    float bs[4];
#pragma unroll
    for (int reg = 0; reg < 4; ++reg) bs[reg] = bias[mbase + reg];
#pragma unroll
    for (int st = 0; st < 4; ++st) {
        int t = t0 + (wt2 * 4 + st) * 16 + col;
        float v[4];
#pragma unroll
        for (int reg = 0; reg < 4; ++reg) v[reg] = acc[st][reg] + bs[reg];
        if (proj < 2) {
            short* dst = (proj == 0) ? qo : ko;
            int2 pk;
            pk.x = pack2(v[0], v[1]);
            pk.y = pack2(v[2], v[3]);
            *(int2*)(dst + ((size_t)(b * TN + t)) * 192 + mloc) = pk;
        } else {
#pragma unroll
            for (int reg = 0; reg < 4; ++reg)
                vo[((size_t)b * 192 + mloc + reg) * TN + t] = f2bf(v[reg]);
        }
    }
}

// ---------------------------------------------------------------------------
// MFMA bf16 conv (f1, f2). Masked t-tiles: zero-fill output, skip compute.
// R10: 512 threads (8 waves: wm 0..3 owns m-frag, wt2 0..1 owns t-half) --
// same grid/LDS/FLOPs, waves/CU 12->24. Verified -26.7us.
// ---------------------------------------------------------------------------
template <int TAPS, int TT, bool RELU, bool MASK_OUT, int OUTK, int KSPLIT>
__global__ __launch_bounds__(512) void k_mgemm(
        const short* __restrict__ W, const short* __restrict__ X,
        const float* __restrict__ bias, void* __restrict__ Yv,
        float* __restrict__ Yv2, float* __restrict__ Yv3,
        const int* __restrict__ lens, int M, int Cin) {
    constexpr int P = (TAPS - 1) / 2;
    constexpr int NST = TT / 16;
    constexpr int NST2 = NST / 2;      // per-wave t-frags
    __shared__ short Wt[TAPS][64][72];
    __shared__ short Xt[TT + 2 * P][72];

    const int b = blockIdx.z;
    const int mtiles = gridDim.y / KSPLIT;
    const int kg = blockIdx.y / mtiles;
    const int m0 = (blockIdx.y % mtiles) * 64;
    const int t0 = blockIdx.x * TT;
    const int len = lens[b];
    const int tid = threadIdx.x;
    const int wave = tid >> 6;
    const int lane = tid & 63;
    const int col = lane & 15;
    const int quad = lane >> 4;
    const int wm = wave & 3, wt2 = wave >> 2;  // wm: m-frag, wt2: t-half
    const int mbase = m0 + wm * 16 + quad * 4;

    if (MASK_OUT && t0 >= len) {
#pragma unroll
        for (int st = 0; st < NST2; ++st) {
            int t = t0 + (wt2 * NST2 + st) * 16 + col;
            if (OUTK == 0) {
                float* dst = (KSPLIT > 1) ? (kg == 0 ? (float*)Yv : (kg == 1 ? Yv2 : Yv3))
                                          : (float*)Yv;
#pragma unroll
                for (int reg = 0; reg < 4; ++reg)
                    dst[((size_t)b * M + mbase + reg) * TN + t] = 0.f;
            } else {
                int2 z = {0, 0};
                *(int2*)((short*)Yv + ((size_t)(b * TN + t)) * M + mbase) = z;
            }
        }
        return;
    }

    f32x4 acc[NST2];
#pragma unroll
    for (int st = 0; st < NST2; ++st) acc[st] = (f32x4){0.f, 0.f, 0.f, 0.f};

    const int cspan = Cin / KSPLIT;
    const int cbeg = kg * cspan;
    const int cend = cbeg + cspan;
    for (int c0 = cbeg; c0 < cend; c0 += 64) {
        __syncthreads();
        for (int i = tid; i < TAPS * 64 * 8; i += 512) {
            int tap = i / (64 * 8);
            int mm = (i / 8) & 63;
            int part = i & 7;
            *(int4*)(&Wt[tap][mm][part * 8]) =
                *(const int4*)(W + ((size_t)tap * M + m0 + mm) * Cin + c0 + part * 8);
        }
        for (int i = tid; i < (TT + 2 * P) * 8; i += 512) {
            int tt = i >> 3;
            int part = i & 7;
            int t = t0 + tt - P;
            int4 v = {0, 0, 0, 0};
            if (t >= 0 && t < TN)
                v = *(const int4*)(X + ((size_t)b * TN + t) * Cin + c0 + part * 8);
            *(int4*)(&Xt[tt][part * 8]) = v;
        }
        __syncthreads();
#pragma unroll
        for (int ks = 0; ks < 2; ++ks) {
#pragma unroll
            for (int tap = 0; tap < TAPS; ++tap) {
                bfrag af = *(const bfrag*)(&Wt[tap][wm * 16 + col][ks * 32 + quad * 8]);
#pragma unroll
                for (int st = 0; st < NST2; ++st) {
                    bfrag bf = *(const bfrag*)(&Xt[(wt2 * NST2 + st) * 16 + col + tap][ks * 32 + quad * 8]);
                    acc[st] = __builtin_amdgcn_mfma_f32_16x16x32_bf16(af, bf, acc[st], 0, 0, 0);
                }
            }
        }
    }

    float bs[4];
#pragma unroll
    for (int reg = 0; reg < 4; ++reg)
        bs[reg] = (KSPLIT > 1 && kg) ? 0.f : bias[mbase + reg];
#pragma unroll
    for (int st = 0; st < NST2; ++st) {
        int t = t0 + (wt2 * NST2 + st) * 16 + col;
        bool om = MASK_OUT && (t >= len);
        float v[4];
#pragma unroll
        for (int reg = 0; reg < 4; ++reg) {
            float u = acc[st][reg] + bs[reg];
            if (RELU) u = fmaxf(u, 0.f);
            if (om) u = 0.f;
            v[reg] = u;
        }
        if (OUTK == 0) {
            float* dst = (KSPLIT > 1) ? (kg == 0 ? (float*)Yv : (kg == 1 ? Yv2 : Yv3))
                                      : (float*)Yv;
#pragma unroll
            for (int reg = 0; reg < 4; ++reg)
                dst[((size_t)b * M + mbase + reg) * TN + t] = v[reg];
        } else {
            int2 pk;
            pk.x = pack2(v[0], v[1]);
            pk.y = pack2(v[2], v[3]);
            *(int2*)((short*)Yv + ((size_t)(b * TN + t)) * M + mbase) = pk;
        }
    }
}

// ---------------------------------------------------------------------------
// MFMA bf16 flash attention, partial-sum formulation.
// Masked q-tiles: write lP=0 (merge linv=0 kills stale accP) and return.
// sband stores p (not v) -> epilogue has no exp. NO register prefetch here:
// it spills under the 128-VGPR launch_bounds cap (R2: +19us).
// ---------------------------------------------------------------------------
__global__ __launch_bounds__(512, 4) void k_attn4(
        const short* __restrict__ Q, const short* __restrict__ K,
        const short* __restrict__ V, const float* __restrict__ relk,
        const float* __restrict__ relv, short* __restrict__ accP,
        float* __restrict__ lP, const int* __restrict__ lens) {
    __shared__ short kt[64 * QSTR];
    __shared__ short vt[96 * 72];
    __shared__ short Pt[128 * 72];
    __shared__ short rbt[16 * QSTR];   // relk as bf16 B-tile (rows 9..15 zero)
    __shared__ float rels[128 * 12];
    __shared__ float sband[128 * 12];  // stores p (post-mask softmax numerator)
    __shared__ float rvs[9 * 96];

    const int b = blockIdx.z;
    const int h = blockIdx.y >> 2, sh = blockIdx.y & 3;
    const int t0 = blockIdx.x * 128;
    const int len = lens[b];
    const int tid = threadIdx.x;
    const int w = tid >> 6;
    const int lane = tid & 63;
    const int col = lane & 15;
    const int quad = lane >> 4;

    if (t0 >= len) {
        if (tid < 128)
            lP[(((size_t)sh * BN + b) * NHN + h) * TN + t0 + tid] = 0.f;
        return;
    }

    const short* Qb = Q + ((size_t)b * TN + t0) * HN + h * KCN;
    const short* Kb = K + ((size_t)b * TN + sh * 256) * HN + h * KCN;
    const short* Vb = V + ((size_t)b * HN + h * KCN) * TN + sh * 256;

    bfrag qf[3];
#pragma unroll
    for (int ks = 0; ks < 3; ++ks)
        qf[ks] = *(const bfrag*)(Qb + (size_t)(w * 16 + col) * HN + ks * 32 + quad * 8);

    for (int i = tid; i < 9 * 96; i += 512) rvs[i] = relv[i];
    for (int i = tid; i < 16 * 96; i += 512) {
        int r = i / 96, c = i % 96;
        rbt[r * QSTR + c] = (r < 9) ? f2bf(relk[r * 96 + c]) : (short)0;
    }
    for (int i = tid; i < 128 * 12; i += 512) sband[i] = 0.f;
    __syncthreads();

    {
        f32x4 rc = (f32x4){0.f, 0.f, 0.f, 0.f};
#pragma unroll
        for (int ks = 0; ks < 3; ++ks) {
            bfrag bf = *(const bfrag*)(rbt + col * QSTR + ks * 32 + quad * 8);
            rc = __builtin_amdgcn_mfma_f32_16x16x32_bf16(qf[ks], bf, rc, 0, 0, 0);
        }
        if (col < 12) {
#pragma unroll
            for (int reg = 0; reg < 4; ++reg)
                rels[(w * 16 + quad * 4 + reg) * 12 + col] = rc[reg];
        }
    }

    float lsum[4];
    f32x4 accv[6];
#pragma unroll
    for (int r = 0; r < 4; ++r) lsum[r] = 0.f;
#pragma unroll
    for (int n = 0; n < 6; ++n) accv[n] = (f32x4){0.f, 0.f, 0.f, 0.f};

    const int rem = len - sh * 256;
    const int nj = (rem <= 0) ? 0 : ((rem >= 256) ? 4 : ((rem + 63) >> 6));

    for (int j = 0; j < nj; ++j) {
        const int s0g = sh * 256 + j * 64;
        __syncthreads();
        for (int i = tid; i < 768; i += 512) {
            int row = i / 12, part = i % 12;
            *(int4*)(kt + row * QSTR + part * 8) =
                *(const int4*)(Kb + ((size_t)(j * 64 + row)) * HN + part * 8);
        }
        for (int i = tid; i < 768; i += 512) {
            int c = i >> 3, part = i & 7;
            *(int4*)(vt + c * 72 + part * 8) =
                *(const int4*)(Vb + (size_t)c * TN + j * 64 + part * 8);
        }
        __syncthreads();

        f32x4 sacc[4];
#pragma unroll
        for (int st = 0; st < 4; ++st) sacc[st] = (f32x4){0.f, 0.f, 0.f, 0.f};
#pragma unroll
        for (int ks = 0; ks < 3; ++ks) {
#pragma unroll
            for (int st = 0; st < 4; ++st) {
                bfrag bf = *(const bfrag*)(kt + (st * 16 + col) * QSTR + ks * 32 + quad * 8);
                sacc[st] = __builtin_amdgcn_mfma_f32_16x16x32_bf16(qf[ks], bf, sacc[st], 0, 0, 0);
            }
        }

#pragma unroll
        for (int reg = 0; reg < 4; ++reg) {
            const int lq = w * 16 + quad * 4 + reg;
            const int qg = t0 + lq;
#pragma unroll
            for (int st = 0; st < 4; ++st) {
                int sg = s0g + st * 16 + col;
                float v = sacc[st][reg];
                int d = sg - qg + 4;
                bool inb = (d >= 0) && (d <= 8);
                if (inb) v += rels[lq * 12 + d];
                if (sg >= len) v = -1e4f;
                float p = __expf(v - M0S);
                if (inb) sband[lq * 12 + d] = p;
                lsum[reg] += p;
                Pt[lq * 72 + st * 16 + col] = f2bf(p);
            }
        }
#pragma unroll
        for (int ks = 0; ks < 2; ++ks) {
            bfrag af = *(const bfrag*)(Pt + (w * 16 + col) * 72 + ks * 32 + quad * 8);
#pragma unroll
            for (int nt = 0; nt < 6; ++nt) {
                bfrag bf = *(const bfrag*)(vt + (nt * 16 + col) * 72 + ks * 32 + quad * 8);
                accv[nt] = __builtin_amdgcn_mfma_f32_16x16x32_bf16(af, bf, accv[nt], 0, 0, 0);
            }
        }
    }

#pragma unroll
    for (int reg = 0; reg < 4; ++reg) {
        lsum[reg] += __shfl_xor(lsum[reg], 1);
        lsum[reg] += __shfl_xor(lsum[reg], 2);
        lsum[reg] += __shfl_xor(lsum[reg], 4);
        lsum[reg] += __shfl_xor(lsum[reg], 8);
    }
    __syncthreads();

    short* aout = accP + (size_t)sh * BN * TN * HN;
#pragma unroll
    for (int reg = 0; reg < 4; ++reg) {
        const int lq = w * 16 + quad * 4 + reg;
        const int qg = t0 + lq;
        float pb[9];
#pragma unroll
        for (int d = 0; d < 9; ++d)
            pb[d] = sband[lq * 12 + d];
#pragma unroll
        for (int nt = 0; nt < 6; ++nt) {
            int c = nt * 16 + col;
            float r = accv[nt][reg];
#pragma unroll
            for (int d = 0; d < 9; ++d) r += pb[d] * rvs[d * 96 + c];
            aout[((size_t)(b * TN + qg)) * HN + h * KCN + c] = f2bf(r);
        }
        if (col == 0)
            lP[(((size_t)sh * BN + b) * NHN + h) * TN + qg] = lsum[reg];
    }
}

// ---------------------------------------------------------------------------
// Residual + LayerNorm: x = LN(x + y [+ y2 [+ y3]])*g + b, fp32 in-place;
// masked bf16 t-major copy xb. Fully-masked tiles: zero xb only (x is dead).
// R8: 512 threads + float4 loads/stores + int2 xb writes. Verified -11.5us.
// ---------------------------------------------------------------------------
template <int NADD>
__global__ __launch_bounds__(512) void k_ln(float* __restrict__ x,
        const float* __restrict__ y, const float* __restrict__ y2,
        const float* __restrict__ y3, const float* __restrict__ g,
        const float* __restrict__ bb, short* __restrict__ xb,
        const int* __restrict__ lens) {
    __shared__ float s[HN][33];
    __shared__ float red1[512], red2[512];
    __shared__ float mu[32], rs[32];
    const int b = blockIdx.y;
    const int t0 = blockIdx.x * 32;
    const int tid = threadIdx.x;
    const int len = lens[b];

    if (t0 >= len) {
        for (int i = tid; i < 32 * 48; i += 512) {
            int2 z = {0, 0};
            *(int2*)((int*)xb + ((size_t)(b * TN + t0 + i / 48)) * 96 + (i % 48) * 2) = z;
        }
        return;
    }

    // vectorized gather: 192 ch x 8 float4-groups = 1536 items, 3 per thread
    for (int i = tid; i < HN * 8; i += 512) {
        int c = i >> 3, tq = i & 7;
        size_t gi = ((size_t)b * HN + c) * TN + t0 + tq * 4;
        float4 v = *(const float4*)(x + gi);
        float4 a = *(const float4*)(y + gi);
        v.x += a.x; v.y += a.y; v.z += a.z; v.w += a.w;
        if (NADD >= 2) {
            float4 a2 = *(const float4*)(y2 + gi);
            v.x += a2.x; v.y += a2.y; v.z += a2.z; v.w += a2.w;
        }
        if (NADD >= 3) {
            float4 a3 = *(const float4*)(y3 + gi);
            v.x += a3.x; v.y += a3.y; v.z += a3.z; v.w += a3.w;
        }
        s[c][tq * 4 + 0] = v.x;
        s[c][tq * 4 + 1] = v.y;
        s[c][tq * 4 + 2] = v.z;
        s[c][tq * 4 + 3] = v.w;
    }
    __syncthreads();
    int tt = tid & 31, grp = tid >> 5;  // 16 groups x 12 channels
    float sum = 0.f, sum2 = 0.f;
    for (int c = grp * 12; c < grp * 12 + 12; ++c) {
        float v = s[c][tt];
        sum += v;
        sum2 += v * v;
    }
    red1[tid] = sum;
    red2[tid] = sum2;
    __syncthreads();
    if (tid < 32) {
        float tot = 0.f, tot2 = 0.f;
#pragma unroll
        for (int gg = 0; gg < 16; ++gg) { tot += red1[gg * 32 + tid]; tot2 += red2[gg * 32 + tid]; }
        float mean = tot / (float)HN;
        float var = tot2 / (float)HN - mean * mean;
        mu[tid] = mean;
        rs[tid] = rsqrtf(var + 1e-5f);
    }
    __syncthreads();
    // normalized x (fp32 ch-major, float4)
    for (int i = tid; i < HN * 8; i += 512) {
        int c = i >> 3, tq = i & 7;
        float gc = g[c], bc = bb[c];
        float4 o;
        o.x = (s[c][tq * 4 + 0] - mu[tq * 4 + 0]) * rs[tq * 4 + 0] * gc + bc;
        o.y = (s[c][tq * 4 + 1] - mu[tq * 4 + 1]) * rs[tq * 4 + 1] * gc + bc;
        o.z = (s[c][tq * 4 + 2] - mu[tq * 4 + 2]) * rs[tq * 4 + 2] * gc + bc;
        o.w = (s[c][tq * 4 + 3] - mu[tq * 4 + 3]) * rs[tq * 4 + 3] * gc + bc;
        *(float4*)(x + ((size_t)b * HN + c) * TN + t0 + tq * 4) = o;
    }
    // xb bf16 t-major, int2-packed (4 channels per item), masked
    for (int i = tid; i < 32 * 48; i += 512) {
        int t2 = i / 48, p2 = i % 48;
        int c0 = p2 * 4;
        float m = mu[t2], r = rs[t2];
        float v0 = (s[c0][t2] - m) * r * g[c0] + bb[c0];
        float v1 = (s[c0 + 1][t2] - m) * r * g[c0 + 1] + bb[c0 + 1];
        float v2 = (s[c0 + 2][t2] - m) * r * g[c0 + 2] + bb[c0 + 2];
        float v3 = (s[c0 + 3][t2] - m) * r * g[c0 + 3] + bb[c0 + 3];
        if (t0 + t2 >= len) { v0 = 0.f; v1 = 0.f; v2 = 0.f; v3 = 0.f; }
        int2 pk;
        pk.x = pack2(v0, v1);
        pk.y = pack2(v2, v3);
        *(int2*)((int*)xb + ((size_t)(b * TN + t0 + t2)) * 96 + p2 * 2) = pk;
    }
}

// ---------------------------------------------------------------------------
// Fused stats projection + final sampling.
// R11: 512 threads (wm x wt2 wave split). Verified (part of -22.9us).
// ---------------------------------------------------------------------------
__global__ __launch_bounds__(512) void k_statsfin(
        const short* __restrict__ W, const short* __restrict__ X,
        const float* __restrict__ bias, const float* __restrict__ x,
        const float* __restrict__ eps, const int* __restrict__ lens,
        float* __restrict__ out) {
    __shared__ short Wt[64 * GSTR];
    __shared__ short Xt[64 * GSTR];
    const int b = blockIdx.z, o0 = blockIdx.y * 64, t0 = blockIdx.x * 64;
    const int len = lens[b];
    const int tid = threadIdx.x;
    const int wave = tid >> 6, lane = tid & 63, col = lane & 15, quad = lane >> 4;
    const int wm = wave & 3, wt2 = wave >> 2;  // wm: o-frag, wt2: t-half
    const size_t S = (size_t)BN * OUTN * TN;

    if (t0 >= len) {
        for (int i = tid; i < 4096; i += 512) {
            int oo = i >> 6, tt = i & 63;
            size_t idx = ((size_t)b * OUTN + o0 + oo) * TN + t0 + tt;
            out[idx] = 0.f;
            out[S + idx] = 0.f;
            out[2 * S + idx] = 0.f;
            out[3 * S + idx] = 0.f;
        }
        if (o0 == 0 && tid < 64) out[4 * S + (size_t)b * TN + t0 + tid] = 0.f;
        return;
    }

    for (int i = tid; i < 1536; i += 512) {
        int tt = i / 24, part = i % 24;
        *(int4*)(Xt + tt * GSTR + part * 8) =
            *(const int4*)(X + ((size_t)(b * TN + t0 + tt)) * 192 + part * 8);
    }
    for (int i = tid; i < 1536; i += 512) {
        int mm = i / 24, part = i % 24;
        *(int4*)(Wt + mm * GSTR + part * 8) =
            *(const int4*)(W + ((size_t)(o0 + mm)) * 192 + part * 8);
    }
    __syncthreads();

    f32x4 am[2];
#pragma unroll
    for (int st = 0; st < 2; ++st) am[st] = (f32x4){0.f, 0.f, 0.f, 0.f};
#pragma unroll
    for (int ks = 0; ks < 6; ++ks) {
        bfrag af = *(const bfrag*)(Wt + (wm * 16 + col) * GSTR + ks * 32 + quad * 8);
#pragma unroll
        for (int st = 0; st < 2; ++st) {
            bfrag bf = *(const bfrag*)(Xt + ((wt2 * 2 + st) * 16 + col) * GSTR + ks * 32 + quad * 8);
            am[st] = __builtin_amdgcn_mfma_f32_16x16x32_bf16(af, bf, am[st], 0, 0, 0);
        }
    }
    __syncthreads();
    for (int i = tid; i < 1536; i += 512) {
        int mm = i / 24, part = i % 24;
        *(int4*)(Wt + mm * GSTR + part * 8) =
            *(const int4*)(W + ((size_t)(192 + o0 + mm)) * 192 + part * 8);
    }
    __syncthreads();

    f32x4 al[2];
#pragma unroll
    for (int st = 0; st < 2; ++st) al[st] = (f32x4){0.f, 0.f, 0.f, 0.f};
#pragma unroll
    for (int ks = 0; ks < 6; ++ks) {
        bfrag af = *(const bfrag*)(Wt + (wm * 16 + col) * GSTR + ks * 32 + quad * 8);
#pragma unroll
        for (int st = 0; st < 2; ++st) {
            bfrag bf = *(const bfrag*)(Xt + ((wt2 * 2 + st) * 16 + col) * GSTR + ks * 32 + quad * 8);
            al[st] = __builtin_amdgcn_mfma_f32_16x16x32_bf16(af, bf, al[st], 0, 0, 0);
        }
    }

    const int obase = o0 + wm * 16 + quad * 4;
    float bm[4], bl[4];
#pragma unroll
    for (int reg = 0; reg < 4; ++reg) {
        bm[reg] = bias[obase + reg];
        bl[reg] = bias[192 + obase + reg];
    }
#pragma unroll
    for (int st = 0; st < 2; ++st) {
        int t = t0 + (wt2 * 2 + st) * 16 + col;
        bool om = (t >= len);
#pragma unroll
        for (int reg = 0; reg < 4; ++reg) {
            float m = am[st][reg] + bm[reg];
            float ls = al[st][reg] + bl[reg];
            if (om) { m = 0.f; ls = 0.f; }
            size_t idx = ((size_t)b * OUTN + obase + reg) * TN + t;
            float e = eps[idx];
            out[idx] = om ? 0.f : m + e * __expf(ls);
            out[S + idx] = m;
            out[2 * S + idx] = ls;
        }
    }
    for (int i = tid; i < 4096; i += 512) {
        int oo = i >> 6, tt = i & 63;
        int t = t0 + tt;
        float mv = (t < len) ? 1.f : 0.f;
        size_t idx = ((size_t)b * OUTN + o0 + oo) * TN + t;
        out[3 * S + idx] = x[((size_t)b * HN + o0 + oo) * TN + t] * mv;
    }
    if (o0 == 0 && tid < 64)
        out[4 * S + (size_t)b * TN + t0 + tid] = (t0 + tid < len) ? 1.f : 0.f;
}

// ---------------------------------------------------------------------------
extern "C" void kernel_launch(void* const* d_in, const int* in_sizes, int n_in,
                              void* d_out, int out_size, void* d_ws, size_t ws_size,
                              hipStream_t stream) {
    const int* tok = (const int*)d_in[0];
    const int* lens = (const int*)d_in[1];
    const float* emb = (const float*)d_in[2];
    const float* qw = (const float*)d_in[3];
    const float* qb = (const float*)d_in[4];
    const float* kw = (const float*)d_in[5];
    const float* kb = (const float*)d_in[6];
    const float* vw = (const float*)d_in[7];
    const float* vb = (const float*)d_in[8];
    const float* ow = (const float*)d_in[9];
    const float* ob = (const float*)d_in[10];
    const float* relk = (const float*)d_in[11];
    const float* relv = (const float*)d_in[12];
    const float* ln1g = (const float*)d_in[13];
    const float* ln1b = (const float*)d_in[14];
    const float* f1w = (const float*)d_in[15];
    const float* f1b = (const float*)d_in[16];
    const float* f2w = (const float*)d_in[17];
    const float* f2b = (const float*)d_in[18];
    const float* ln2g = (const float*)d_in[19];
    const float* ln2b = (const float*)d_in[20];
    const float* pw = (const float*)d_in[21];
    const float* pb = (const float*)d_in[22];
    const float* eps = (const float*)d_in[23];

    const size_t BHT = (size_t)BN * HN * TN; // 1,572,864
    float* ws = (float*)d_ws;
    float* x = ws;                                   // fp32 ch-major
    float* yf = ws + BHT;                            // fp32 ch-major (f2 kg=0)
    short* s_xb = (short*)(ws + 2 * BHT);            // bf16 t-major (qkv/stats in)
    short* s_ln = (short*)(ws + 2 * BHT + BHT / 2);  // bf16 t-major (f1 in)
    short* s_q  = (short*)(ws + 3 * BHT);
    short* s_k  = (short*)(ws + 3 * BHT + BHT / 2);
    short* s_v  = (short*)(ws + 4 * BHT);
    float* p1   = ws + 3 * BHT;   // f2 partial kg=1 (overlays s_q/s_k: dead by then)
    float* p2   = ws + 4 * BHT;   // f2 partial kg=2 (overlays s_v + free slot)
    short* accP = (short*)(ws + 5 * BHT);            // 4 x BHT shorts (attn partials)
    short* s_y1 = (short*)(ws + 5 * BHT);            // f1 out (B,T,FFN), after attn consumed
    short* wqkv = (short*)(ws + 7 * BHT);            // [L][576][192]
    short* wo16 = wqkv + (size_t)LN * 3 * HN * HN;
    short* wp16 = wo16 + (size_t)LN * HN * HN;
    short* wf1_16 = wp16 + (size_t)2 * OUTN * HN;
    short* wf2_16 = wf1_16 + (size_t)LN * 3 * FFNN * HN;
    float* bqkv = (float*)(wf2_16 + (size_t)LN * 3 * FFNN * HN);  // [L][576]
    float* lP = bqkv + (size_t)LN * 576;             // 4 x B x NH x T floats

    // fused weight conversion (single launch)
    {
        long total = (long)LN * 576 * 192 + LN * 576 + LN * HN * HN + 2 * OUTN * HN
                   + 2L * LN * FFNN * HN * 3;
        k_cvtall<<<dim3((unsigned)((total + 255) / 256)), 256, 0, stream>>>(
            qw, kw, vw, qb, kb, vb, ow, pw, f1w, f2w,
            wqkv, bqkv, wo16, wp16, wf1_16, wf2_16);
    }

    dim3 gemb(TN / 16, BN);             // 64 x 8 (2 blocks/CU for token gather)
    k_embed<<<gemb, 256, 0, stream>>>(tok, lens, emb, x, s_xb);

    dim3 gqkv(TN / 128, 9, BN);         // 8 x 9 x 8 (512 thr)
    dim3 gattn(TN / 128, NHN * 4, BN);  // 8 x 8 x 8 (512-thread blocks)
    dim3 gol(TN / 32, BN);              // 32 x 8 (fused oproj+merge+LN1, 512 thr)
    dim3 gf1(TN / 128, FFNN / 64, BN);  // 8 x 12 x 8 (512 thr)
    dim3 gf2(TN / 128, 9, BN);          // 8 x (3m x 3kg) x 8 (512 thr)
    dim3 gln(TN / 32, BN);              // 32 x 8 (512 thr)

    for (int i = 0; i < LN; ++i) {
        const short* qkvwi = wqkv + (size_t)i * 576 * 192;
        const float* qkvbi = bqkv + (size_t)i * 576;
        const short* owi = wo16 + (size_t)i * HN * HN;
        const short* f1wi = wf1_16 + (size_t)i * 3 * FFNN * HN;
        const short* f2wi = wf2_16 + (size_t)i * 3 * FFNN * HN;
        const float* obi = ob + (size_t)i * HN;
        const float* rki = relk + (size_t)i * 9 * KCN;
        const float* rvi = relv + (size_t)i * 9 * KCN;
        const float* l1gi = ln1g + (size_t)i * HN;
        const float* l1bi = ln1b + (size_t)i * HN;
        const float* f1bi = f1b + (size_t)i * FFNN;
        const float* f2bi = f2b + (size_t)i * HN;
        const float* l2gi = ln2g + (size_t)i * HN;
        const float* l2bi = ln2b + (size_t)i * HN;

        k_qkv2<<<gqkv, 512, 0, stream>>>(qkvwi, s_xb, qkvbi, s_q, s_k, s_v, lens);
        k_attn4<<<gattn, 512, 0, stream>>>(s_q, s_k, s_v, rki, rvi, accP, lP, lens);
        k_oln<<<gol, 512, 0, stream>>>(owi, obi, accP, lP, x, l1gi, l1bi, s_ln, lens);
        k_mgemm<3, 128, true, true, 1, 1><<<gf1, 512, 0, stream>>>(f1wi, s_ln, f1bi, s_y1, nullptr, nullptr, lens, FFNN, HN);
        k_mgemm<3, 128, false, true, 0, 3><<<gf2, 512, 0, stream>>>(f2wi, s_y1, f2bi, yf, p1, p2, lens, HN, FFNN);
        k_ln<3><<<gln, 512, 0, stream>>>(x, yf, p1, p2, l2gi, l2bi, s_xb, lens);
    }

    dim3 gsf(TN / 64, OUTN / 64, BN);   // 16 x 3 x 8 (512 thr)
    k_statsfin<<<gsf, 512, 0, stream>>>(wp16, s_xb, pb, x, eps, lens, (float*)d_out);
}

// Round 15
// 756.410 us; speedup vs baseline: 1.0162x; 1.0053x over previous
//
#include <hip/hip_runtime.h>
#include <math.h>

#define BN 8
#define TN 1024
#define HN 192
#define NHN 2
#define KCN 96
#define LN 6
#define FFNN 768
#define OUTN 192
#define QSTR 104  // kt/rbt LDS row stride in shorts: 13 granules (odd) -> conflict-free b128
#define GSTR 200  // K=192 GEMM LDS row stride (192 data + pad): 25 granules (odd)
#define M0S 12.0f // fixed softmax shift: scores are O(1); exp(s-12) safe to s~100

typedef short bfrag __attribute__((ext_vector_type(8)));
typedef float f32x4 __attribute__((ext_vector_type(4)));

__device__ __forceinline__ short f2bf(float f) {
    union { float f; unsigned u; } v; v.f = f;
    unsigned r = v.u + 0x7fffu + ((v.u >> 16) & 1u);
    return (short)(r >> 16);
}
__device__ __forceinline__ float bf2f(short s) {
    union { unsigned u; float f; } v;
    v.u = ((unsigned)(unsigned short)s) << 16;
    return v.f;
}
__device__ __forceinline__ int pack2(float a, float b) {
    return (int)(unsigned short)f2bf(a) | (((int)(unsigned short)f2bf(b)) << 16);
}

#define QSCALE 0.10206207261596575f  // 1/sqrt(96)

// ---------------------------------------------------------------------------
// Fused weight conversions (one launch).
// ---------------------------------------------------------------------------
__global__ void k_cvtall(const float* __restrict__ qw, const float* __restrict__ kw,
        const float* __restrict__ vw, const float* __restrict__ qb,
        const float* __restrict__ kb, const float* __restrict__ vb,
        const float* __restrict__ ow, const float* __restrict__ pw,
        const float* __restrict__ f1w, const float* __restrict__ f2w,
        short* __restrict__ wqkv, float* __restrict__ bqkv,
        short* __restrict__ wo16, short* __restrict__ wp16,
        short* __restrict__ wf1, short* __restrict__ wf2) {
    const int N0 = LN * 576 * 192;
    const int N1 = LN * 576;
    const int N2 = LN * HN * HN;
    const int N3 = 2 * OUTN * HN;
    const int N4 = LN * FFNN * HN * 3;
    int i = blockIdx.x * 256 + threadIdx.x;
    if (i < N0) {
        int c = i % 192, r = (i / 192) % 576, l = i / (192 * 576);
        float val, sc = 1.f;
        if (r < 192) { val = qw[((size_t)l * 192 + r) * 192 + c]; sc = QSCALE; }
        else if (r < 384) val = kw[((size_t)l * 192 + (r - 192)) * 192 + c];
        else val = vw[((size_t)l * 192 + (r - 384)) * 192 + c];
        wqkv[i] = f2bf(val * sc);
        return;
    }
    i -= N0;
    if (i < N1) {
        int r = i % 576, l = i / 576;
        bqkv[i] = (r < 192) ? qb[l * 192 + r] * QSCALE
                : (r < 384) ? kb[l * 192 + r - 192]
                            : vb[l * 192 + r - 384];
        return;
    }
    i -= N1;
    if (i < N2) { wo16[i] = f2bf(ow[i]); return; }
    i -= N2;
    if (i < N3) { wp16[i] = f2bf(pw[i]); return; }
    i -= N3;
    if (i < N4) {
        int tap = i % 3, c = (i / 3) % HN, m = (i / (3 * HN)) % FFNN, l = i / (3 * HN * FFNN);
        wf1[(((size_t)l * 3 + tap) * FFNN + m) * HN + c] = f2bf(f1w[i]);
        return;
    }
    i -= N4;
    if (i < N4) {
        int tap = i % 3, c = (i / 3) % FFNN, m = (i / (3 * FFNN)) % HN, l = i / (3 * FFNN * HN);
        wf2[(((size_t)l * 3 + tap) * HN + m) * FFNN + c] = f2bf(f2w[i]);
    }
}

// ---------------------------------------------------------------------------
// Embedding: x fp32 ch-major (B,H,T) + xb bf16 t-major (B,T,H), both masked.
// R11: 16-t tiles, grid 512 (2 blocks/CU). Verified.
// ---------------------------------------------------------------------------
__global__ __launch_bounds__(256) void k_embed(const int* __restrict__ tok,
        const int* __restrict__ lens, const float* __restrict__ emb,
        float* __restrict__ x, short* __restrict__ xb) {
    __shared__ float s[HN][17];
    const int b = blockIdx.y, t0 = blockIdx.x * 16, tid = threadIdx.x;
    const int len = lens[b];
    for (int idx = tid; idx < 16 * HN; idx += 256) {
        int tt = idx / HN, c = idx % HN;
        int t = t0 + tt;
        float v = 0.f;
        if (t < len) v = emb[tok[b * TN + t] * HN + c] * 13.856406460551018f; // sqrt(192)
        s[c][tt] = v;
    }
    __syncthreads();
    for (int idx = tid; idx < 16 * HN; idx += 256) {
        int c = idx >> 4, tt = idx & 15;
        x[((size_t)b * HN + c) * TN + t0 + tt] = s[c][tt];
    }
    for (int idx = tid; idx < 16 * 96; idx += 256) {
        int tt = idx / 96, p = idx % 96;
        ((int*)xb)[((size_t)(b * TN + t0 + tt)) * 96 + p] = pack2(s[2 * p][tt], s[2 * p + 1][tt]);
    }
}

// ---------------------------------------------------------------------------
// Fused o-proj + merge + residual + LN1, 512 threads (wm x wt), LDS-staged W,
// hoisted x residual staging. Verified (R11 form, 760.4us total).
// ---------------------------------------------------------------------------
__global__ __launch_bounds__(512, 2) void k_oln(
        const short* __restrict__ W, const float* __restrict__ bias,
        const short* __restrict__ accP, const float* __restrict__ lPp,
        float* __restrict__ x, const float* __restrict__ g,
        const float* __restrict__ bb, short* __restrict__ xb,
        const int* __restrict__ lens) {
    __shared__ short Wt[192 * GSTR];   // 76.8 KB
    __shared__ short Xt[32 * GSTR];    // 12.8 KB
    __shared__ float s_out[HN][33];    // 25.3 KB (x stage, then LN output)
    __shared__ float linv[64];
    __shared__ float red1[32 * 16], red2[32 * 16];
    __shared__ float mu[32], rs[32];
    const int b = blockIdx.y, t0 = blockIdx.x * 32;
    const int len = lens[b];
    const int tid = threadIdx.x;
    const int wave = tid >> 6, lane = tid & 63, col = lane & 15, quad = lane >> 4;
    const int wm = wave & 3, wt = wave >> 2;   // wm: m-frag group, wt: t-strip

    if (t0 >= len) {
        for (int idx = tid; idx < 32 * 96; idx += 512)
            ((int*)xb)[((size_t)(b * TN + t0 + idx / 96)) * 96 + idx % 96] = 0;
        return;
    }

    if (tid < 64) {
        int tt = tid & 31, h = tid >> 5;
        float l = 0.f;
#pragma unroll
        for (int sh = 0; sh < 4; ++sh)
            l += lPp[(((size_t)sh * BN + b) * NHN + h) * TN + t0 + tt];
        linv[tid] = (l > 0.f) ? 1.f / l : 0.f;
    }
    // stage W (192 x 24 granules)
    for (int i = tid; i < 4608; i += 512) {
        int mm = i / 24, part = i % 24;
        *(int4*)(Wt + mm * GSTR + part * 8) =
            *(const int4*)(W + ((size_t)mm) * 192 + part * 8);
    }
    // stage x tile for residual add (hoisted: hides under merge+MFMA)
    for (int i = tid; i < 6144; i += 512) {
        int c = i >> 5, tt = i & 31;
        s_out[c][tt] = x[((size_t)b * HN + c) * TN + t0 + tt];
    }
    __syncthreads();  // linv ready for merge; W/s_out published
    // merge accP -> Xt (32 x 24 granules), once per t
    const size_t HSq = (size_t)BN * TN * HN;
    for (int i = tid; i < 768; i += 512) {
        int tt = i / 24, part = i % 24;
        const size_t base = ((size_t)(b * TN + t0 + tt)) * 192 + part * 8;
        float a[8];
#pragma unroll
        for (int c = 0; c < 8; ++c) a[c] = 0.f;
#pragma unroll
        for (int sh = 0; sh < 4; ++sh) {
            int4 v = *(const int4*)(accP + sh * HSq + base);
            const short* sv = (const short*)&v;
#pragma unroll
            for (int c = 0; c < 8; ++c) a[c] += bf2f(sv[c]);
        }
        float li = linv[(part >= 12 ? 32 : 0) + tt];
        int4 o;
        int* oi = (int*)&o;
#pragma unroll
        for (int c = 0; c < 4; ++c) oi[c] = pack2(a[2 * c] * li, a[2 * c + 1] * li);
        *(int4*)(Xt + tt * GSTR + part * 8) = o;
    }
    __syncthreads();

    f32x4 acc[3];
#pragma unroll
    for (int mf3 = 0; mf3 < 3; ++mf3) acc[mf3] = (f32x4){0.f, 0.f, 0.f, 0.f};
#pragma unroll
    for (int ks = 0; ks < 6; ++ks) {
        bfrag bfx = *(const bfrag*)(Xt + (wt * 16 + col) * GSTR + ks * 32 + quad * 8);
#pragma unroll
        for (int mf3 = 0; mf3 < 3; ++mf3) {
            int mf = mf3 * 4 + wm;
            bfrag af = *(const bfrag*)(Wt + (mf * 16 + col) * GSTR + ks * 32 + quad * 8);
            acc[mf3] = __builtin_amdgcn_mfma_f32_16x16x32_bf16(af, bfx, acc[mf3], 0, 0, 0);
        }
    }

    // residual add + per-t partial stats (each thread owns 12 channels at tcol)
    float bsv[3][4];
#pragma unroll
    for (int mf3 = 0; mf3 < 3; ++mf3)
#pragma unroll
        for (int reg = 0; reg < 4; ++reg)
            bsv[mf3][reg] = bias[(mf3 * 4 + wm) * 16 + quad * 4 + reg];
    {
        const int tcol = wt * 16 + col;
        float s1 = 0.f, s2 = 0.f;
#pragma unroll
        for (int mf3 = 0; mf3 < 3; ++mf3) {
#pragma unroll
            for (int reg = 0; reg < 4; ++reg) {
                int row = (mf3 * 4 + wm) * 16 + quad * 4 + reg;
                float v = acc[mf3][reg] + bsv[mf3][reg] + s_out[row][tcol];
                acc[mf3][reg] = v;
                s1 += v;
                s2 += v * v;
            }
        }
        red1[tcol * 16 + (wm * 4 + quad)] = s1;
        red2[tcol * 16 + (wm * 4 + quad)] = s2;
    }
    __syncthreads();
    if (tid < 32) {
        float tot = 0.f, tot2 = 0.f;
#pragma unroll
        for (int gg = 0; gg < 16; ++gg) {
            tot += red1[tid * 16 + gg];
            tot2 += red2[tid * 16 + gg];
        }
        float mean = tot / (float)HN;
        float var = tot2 / (float)HN - mean * mean;
        mu[tid] = mean;
        rs[tid] = rsqrtf(var + 1e-5f);
    }
    __syncthreads();
    // normalize into s_out (each thread writes its own 12 cells)
    {
        const int tcol = wt * 16 + col;
#pragma unroll
        for (int mf3 = 0; mf3 < 3; ++mf3) {
#pragma unroll
            for (int reg = 0; reg < 4; ++reg) {
                int row = (mf3 * 4 + wm) * 16 + quad * 4 + reg;
                s_out[row][tcol] = (acc[mf3][reg] - mu[tcol]) * rs[tcol] * g[row] + bb[row];
            }
        }
    }
    __syncthreads();
    // coalesced epilogue: x (fp32 ch-major) + xb (bf16 t-major, masked)
    for (int i = tid; i < 6144; i += 512) {
        int c = i >> 5, tt = i & 31;
        x[((size_t)b * HN + c) * TN + t0 + tt] = s_out[c][tt];
    }
    for (int idx = tid; idx < 32 * 96; idx += 512) {
        int t2 = idx / 96, p = idx % 96;
        float v0 = s_out[2 * p][t2], v1 = s_out[2 * p + 1][t2];
        if (t0 + t2 >= len) { v0 = 0.f; v1 = 0.f; }
        ((int*)xb)[((size_t)(b * TN + t0 + t2)) * 96 + p] = pack2(v0, v1);
    }
}

// ---------------------------------------------------------------------------
// R9: fused QKV projection, 128-wide t-tiles, 512 threads (8 waves: wm x wt2).
// Verified. Masking semantics unchanged.
// ---------------------------------------------------------------------------
__global__ __launch_bounds__(512) void k_qkv2(
        const short* __restrict__ W, const short* __restrict__ X,
        const float* __restrict__ bias, short* __restrict__ qo,
        short* __restrict__ ko, short* __restrict__ vo,
        const int* __restrict__ lens) {
    __shared__ short Wt[64 * GSTR];    // 25.6 KB
    __shared__ short Xt[128 * GSTR];   // 51.2 KB
    const int b = blockIdx.z, m0 = blockIdx.y * 64, t0 = blockIdx.x * 128;
    const int len = lens[b];
    const int tid = threadIdx.x;
    const int wave = tid >> 6, lane = tid & 63, col = lane & 15, quad = lane >> 4;
    const int wm = wave & 3, wt2 = wave >> 2;  // wm: m-frag, wt2: t-half
    const int proj = m0 / 192;           // block-uniform: 0=q 1=k 2=v
    const int mbase = m0 + wm * 16 + quad * 4;
    const int mloc = mbase - proj * 192;

    if (t0 >= len) {
        if (proj == 1) return;
#pragma unroll
        for (int st = 0; st < 4; ++st) {
            int t = t0 + (wt2 * 4 + st) * 16 + col;
            if (proj == 0) {
                int2 z = {0, 0};
                *(int2*)(qo + ((size_t)(b * TN + t)) * 192 + mloc) = z;
            } else {
#pragma unroll
                for (int reg = 0; reg < 4; ++reg)
                    vo[((size_t)b * 192 + mloc + reg) * TN + t] = 0;
            }
        }
        return;
    }

    for (int i = tid; i < 1536; i += 512) {
        int mm = i / 24, part = i % 24;
        *(int4*)(Wt + mm * GSTR + part * 8) =
            *(const int4*)(W + ((size_t)(m0 + mm)) * 192 + part * 8);
    }
    for (int i = tid; i < 3072; i += 512) {
        int tt = i / 24, part = i % 24;
        *(int4*)(Xt + tt * GSTR + part * 8) =
            *(const int4*)(X + ((size_t)(b * TN + t0 + tt)) * 192 + part * 8);
    }
    __syncthreads();

    f32x4 acc[4];
#pragma unroll
    for (int st = 0; st < 4; ++st) acc[st] = (f32x4){0.f, 0.f, 0.f, 0.f};
#pragma unroll
    for (int ks = 0; ks < 6; ++ks) {
        bfrag af = *(const bfrag*)(Wt + (wm * 16 + col) * GSTR + ks * 32 + quad * 8);
#pragma unroll
        for (int st = 0; st < 4; ++st) {
            bfrag bf = *(const bfrag*)(Xt + ((wt2 * 4 + st) * 16 + col) * GSTR + ks * 32 + quad * 8);
            acc[st] = __builtin_amdgcn_mfma_f32_16x16x32_bf16(af, bf, acc[st], 0, 0, 0);
        }
    }

    float bs[4];
#pragma unroll
    for (int reg = 0; reg < 4; ++reg) bs[reg] = bias[mbase + reg];
#pragma unroll
    for (int st = 0; st < 4; ++st) {
        int t = t0 + (wt2 * 4 + st) * 16 + col;
        float v[4];
#pragma unroll
        for (int reg = 0; reg < 4; ++reg) v[reg] = acc[st][reg] + bs[reg];
        if (proj < 2) {
            short* dst = (proj == 0) ? qo : ko;
            int2 pk;
            pk.x = pack2(v[0], v[1]);
            pk.y = pack2(v[2], v[3]);
            *(int2*)(dst + ((size_t)(b * TN + t)) * 192 + mloc) = pk;
        } else {
#pragma unroll
            for (int reg = 0; reg < 4; ++reg)
                vo[((size_t)b * 192 + mloc + reg) * TN + t] = f2bf(v[reg]);
        }
    }
}

// ---------------------------------------------------------------------------
// MFMA bf16 conv (f1, f2). Masked t-tiles: zero-fill output, skip compute.
// R10: 512 threads (wm x wt2). Verified -26.7us.
// R15: PBF flag -- kg>0 partials written bf16 (halves p1/p2 traffic; they
// carry no bias and feed only the ln2 sum; GEMM inputs already bf16).
// ---------------------------------------------------------------------------
template <int TAPS, int TT, bool RELU, bool MASK_OUT, int OUTK, int KSPLIT, bool PBF>
__global__ __launch_bounds__(512) void k_mgemm(
        const short* __restrict__ W, const short* __restrict__ X,
        const float* __restrict__ bias, void* __restrict__ Yv,
        float* __restrict__ Yv2, float* __restrict__ Yv3,
        const int* __restrict__ lens, int M, int Cin) {
    constexpr int P = (TAPS - 1) / 2;
    constexpr int NST = TT / 16;
    constexpr int NST2 = NST / 2;      // per-wave t-frags
    __shared__ short Wt[TAPS][64][72];
    __shared__ short Xt[TT + 2 * P][72];

    const int b = blockIdx.z;
    const int mtiles = gridDim.y / KSPLIT;
    const int kg = blockIdx.y / mtiles;
    const int m0 = (blockIdx.y % mtiles) * 64;
    const int t0 = blockIdx.x * TT;
    const int len = lens[b];
    const int tid = threadIdx.x;
    const int wave = tid >> 6;
    const int lane = tid & 63;
    const int col = lane & 15;
    const int quad = lane >> 4;
    const int wm = wave & 3, wt2 = wave >> 2;  // wm: m-frag, wt2: t-half
    const int mbase = m0 + wm * 16 + quad * 4;

    if (MASK_OUT && t0 >= len) {
#pragma unroll
        for (int st = 0; st < NST2; ++st) {
            int t = t0 + (wt2 * NST2 + st) * 16 + col;
            if (OUTK == 0) {
                if (PBF && KSPLIT > 1 && kg > 0) {
                    short* dstp = (short*)(kg == 1 ? Yv2 : Yv3);
#pragma unroll
                    for (int reg = 0; reg < 4; ++reg)
                        dstp[((size_t)b * M + mbase + reg) * TN + t] = 0;
                } else {
                    float* dst = (KSPLIT > 1) ? (kg == 0 ? (float*)Yv : (kg == 1 ? Yv2 : Yv3))
                                              : (float*)Yv;
#pragma unroll
                    for (int reg = 0; reg < 4; ++reg)
                        dst[((size_t)b * M + mbase + reg) * TN + t] = 0.f;
                }
            } else {
                int2 z = {0, 0};
                *(int2*)((short*)Yv + ((size_t)(b * TN + t)) * M + mbase) = z;
            }
        }
        return;
    }

    f32x4 acc[NST2];
#pragma unroll
    for (int st = 0; st < NST2; ++st) acc[st] = (f32x4){0.f, 0.f, 0.f, 0.f};

    const int cspan = Cin / KSPLIT;
    const int cbeg = kg * cspan;
    const int cend = cbeg + cspan;
    for (int c0 = cbeg; c0 < cend; c0 += 64) {
        __syncthreads();
        for (int i = tid; i < TAPS * 64 * 8; i += 512) {
            int tap = i / (64 * 8);
            int mm = (i / 8) & 63;
            int part = i & 7;
            *(int4*)(&Wt[tap][mm][part * 8]) =
                *(const int4*)(W + ((size_t)tap * M + m0 + mm) * Cin + c0 + part * 8);
        }
        for (int i = tid; i < (TT + 2 * P) * 8; i += 512) {
            int tt = i >> 3;
            int part = i & 7;
            int t = t0 + tt - P;
            int4 v = {0, 0, 0, 0};
            if (t >= 0 && t < TN)
                v = *(const int4*)(X + ((size_t)b * TN + t) * Cin + c0 + part * 8);
            *(int4*)(&Xt[tt][part * 8]) = v;
        }
        __syncthreads();
#pragma unroll
        for (int ks = 0; ks < 2; ++ks) {
#pragma unroll
            for (int tap = 0; tap < TAPS; ++tap) {
                bfrag af = *(const bfrag*)(&Wt[tap][wm * 16 + col][ks * 32 + quad * 8]);
#pragma unroll
                for (int st = 0; st < NST2; ++st) {
                    bfrag bf = *(const bfrag*)(&Xt[(wt2 * NST2 + st) * 16 + col + tap][ks * 32 + quad * 8]);
                    acc[st] = __builtin_amdgcn_mfma_f32_16x16x32_bf16(af, bf, acc[st], 0, 0, 0);
                }
            }
        }
    }

    float bs[4];
#pragma unroll
    for (int reg = 0; reg < 4; ++reg)
        bs[reg] = (KSPLIT > 1 && kg) ? 0.f : bias[mbase + reg];
#pragma unroll
    for (int st = 0; st < NST2; ++st) {
        int t = t0 + (wt2 * NST2 + st) * 16 + col;
        bool om = MASK_OUT && (t >= len);
        float v[4];
#pragma unroll
        for (int reg = 0; reg < 4; ++reg) {
            float u = acc[st][reg] + bs[reg];
            if (RELU) u = fmaxf(u, 0.f);
            if (om) u = 0.f;
            v[reg] = u;
        }
        if (OUTK == 0) {
            if (PBF && KSPLIT > 1 && kg > 0) {
                short* dstp = (short*)(kg == 1 ? Yv2 : Yv3);
#pragma unroll
                for (int reg = 0; reg < 4; ++reg)
                    dstp[((size_t)b * M + mbase + reg) * TN + t] = f2bf(v[reg]);
            } else {
                float* dst = (KSPLIT > 1) ? (kg == 0 ? (float*)Yv : (kg == 1 ? Yv2 : Yv3))
                                          : (float*)Yv;
#pragma unroll
                for (int reg = 0; reg < 4; ++reg)
                    dst[((size_t)b * M + mbase + reg) * TN + t] = v[reg];
            }
        } else {
            int2 pk;
            pk.x = pack2(v[0], v[1]);
            pk.y = pack2(v[2], v[3]);
            *(int2*)((short*)Yv + ((size_t)(b * TN + t)) * M + mbase) = pk;
        }
    }
}

// ---------------------------------------------------------------------------
// MFMA bf16 flash attention, partial-sum formulation.
// Masked q-tiles: write lP=0 (merge linv=0 kills stale accP) and return.
// sband stores p (not v) -> epilogue has no exp. NO register prefetch here:
// it spills under the 128-VGPR launch_bounds cap (R2: +19us).
// ---------------------------------------------------------------------------
__global__ __launch_bounds__(512, 4) void k_attn4(
        const short* __restrict__ Q, const short* __restrict__ K,
        const short* __restrict__ V, const float* __restrict__ relk,
        const float* __restrict__ relv, short* __restrict__ accP,
        float* __restrict__ lP, const int* __restrict__ lens) {
    __shared__ short kt[64 * QSTR];
    __shared__ short vt[96 * 72];
    __shared__ short Pt[128 * 72];
    __shared__ short rbt[16 * QSTR];   // relk as bf16 B-tile (rows 9..15 zero)
    __shared__ float rels[128 * 12];
    __shared__ float sband[128 * 12];  // stores p (post-mask softmax numerator)
    __shared__ float rvs[9 * 96];

    const int b = blockIdx.z;
    const int h = blockIdx.y >> 2, sh = blockIdx.y & 3;
    const int t0 = blockIdx.x * 128;
    const int len = lens[b];
    const int tid = threadIdx.x;
    const int w = tid >> 6;
    const int lane = tid & 63;
    const int col = lane & 15;
    const int quad = lane >> 4;

    if (t0 >= len) {
        if (tid < 128)
            lP[(((size_t)sh * BN + b) * NHN + h) * TN + t0 + tid] = 0.f;
        return;
    }

    const short* Qb = Q + ((size_t)b * TN + t0) * HN + h * KCN;
    const short* Kb = K + ((size_t)b * TN + sh * 256) * HN + h * KCN;
    const short* Vb = V + ((size_t)b * HN + h * KCN) * TN + sh * 256;

    bfrag qf[3];
#pragma unroll
    for (int ks = 0; ks < 3; ++ks)
        qf[ks] = *(const bfrag*)(Qb + (size_t)(w * 16 + col) * HN + ks * 32 + quad * 8);

    for (int i = tid; i < 9 * 96; i += 512) rvs[i] = relv[i];
    for (int i = tid; i < 16 * 96; i += 512) {
        int r = i / 96, c = i % 96;
        rbt[r * QSTR + c] = (r < 9) ? f2bf(relk[r * 96 + c]) : (short)0;
    }
    for (int i = tid; i < 128 * 12; i += 512) sband[i] = 0.f;
    __syncthreads();

    {
        f32x4 rc = (f32x4){0.f, 0.f, 0.f, 0.f};
#pragma unroll
        for (int ks = 0; ks < 3; ++ks) {
            bfrag bf = *(const bfrag*)(rbt + col * QSTR + ks * 32 + quad * 8);
            rc = __builtin_amdgcn_mfma_f32_16x16x32_bf16(qf[ks], bf, rc, 0, 0, 0);
        }
        if (col < 12) {
#pragma unroll
            for (int reg = 0; reg < 4; ++reg)
                rels[(w * 16 + quad * 4 + reg) * 12 + col] = rc[reg];
        }
    }

    float lsum[4];
    f32x4 accv[6];
#pragma unroll
    for (int r = 0; r < 4; ++r) lsum[r] = 0.f;
#pragma unroll
    for (int n = 0; n < 6; ++n) accv[n] = (f32x4){0.f, 0.f, 0.f, 0.f};

    const int rem = len - sh * 256;
    const int nj = (rem <= 0) ? 0 : ((rem >= 256) ? 4 : ((rem + 63) >> 6));

    for (int j = 0; j < nj; ++j) {
        const int s0g = sh * 256 + j * 64;
        __syncthreads();
        for (int i = tid; i < 768; i += 512) {
            int row = i / 12, part = i % 12;
            *(int4*)(kt + row * QSTR + part * 8) =
                *(const int4*)(Kb + ((size_t)(j * 64 + row)) * HN + part * 8);
        }
        for (int i = tid; i < 768; i += 512) {
            int c = i >> 3, part = i & 7;
            *(int4*)(vt + c * 72 + part * 8) =
                *(const int4*)(Vb + (size_t)c * TN + j * 64 + part * 8);
        }
        __syncthreads();

        f32x4 sacc[4];
#pragma unroll
        for (int st = 0; st < 4; ++st) sacc[st] = (f32x4){0.f, 0.f, 0.f, 0.f};
#pragma unroll
        for (int ks = 0; ks < 3; ++ks) {
#pragma unroll
            for (int st = 0; st < 4; ++st) {
                bfrag bf = *(const bfrag*)(kt + (st * 16 + col) * QSTR + ks * 32 + quad * 8);
                sacc[st] = __builtin_amdgcn_mfma_f32_16x16x32_bf16(qf[ks], bf, sacc[st], 0, 0, 0);
            }
        }

#pragma unroll
        for (int reg = 0; reg < 4; ++reg) {
            const int lq = w * 16 + quad * 4 + reg;
            const int qg = t0 + lq;
#pragma unroll
            for (int st = 0; st < 4; ++st) {
                int sg = s0g + st * 16 + col;
                float v = sacc[st][reg];
                int d = sg - qg + 4;
                bool inb = (d >= 0) && (d <= 8);
                if (inb) v += rels[lq * 12 + d];
                if (sg >= len) v = -1e4f;
                float p = __expf(v - M0S);
                if (inb) sband[lq * 12 + d] = p;
                lsum[reg] += p;
                Pt[lq * 72 + st * 16 + col] = f2bf(p);
            }
        }
#pragma unroll
        for (int ks = 0; ks < 2; ++ks) {
            bfrag af = *(const bfrag*)(Pt + (w * 16 + col) * 72 + ks * 32 + quad * 8);
#pragma unroll
            for (int nt = 0; nt < 6; ++nt) {
                bfrag bf = *(const bfrag*)(vt + (nt * 16 + col) * 72 + ks * 32 + quad * 8);
                accv[nt] = __builtin_amdgcn_mfma_f32_16x16x32_bf16(af, bf, accv[nt], 0, 0, 0);
            }
        }
    }

#pragma unroll
    for (int reg = 0; reg < 4; ++reg) {
        lsum[reg] += __shfl_xor(lsum[reg], 1);
        lsum[reg] += __shfl_xor(lsum[reg], 2);
        lsum[reg] += __shfl_xor(lsum[reg], 4);
        lsum[reg] += __shfl_xor(lsum[reg], 8);
    }
    __syncthreads();

    short* aout = accP + (size_t)sh * BN * TN * HN;
#pragma unroll
    for (int reg = 0; reg < 4; ++reg) {
        const int lq = w * 16 + quad * 4 + reg;
        const int qg = t0 + lq;
        float pb[9];
#pragma unroll
        for (int d = 0; d < 9; ++d)
            pb[d] = sband[lq * 12 + d];
#pragma unroll
        for (int nt = 0; nt < 6; ++nt) {
            int c = nt * 16 + col;
            float r = accv[nt][reg];
#pragma unroll
            for (int d = 0; d < 9; ++d) r += pb[d] * rvs[d * 96 + c];
            aout[((size_t)(b * TN + qg)) * HN + h * KCN + c] = f2bf(r);
        }
        if (col == 0)
            lP[(((size_t)sh * BN + b) * NHN + h) * TN + qg] = lsum[reg];
    }
}

// ---------------------------------------------------------------------------
// Residual + LayerNorm: x = LN(x + y [+ y2 [+ y3]])*g + b, fp32 in-place;
// masked bf16 t-major copy xb. Fully-masked tiles: zero xb only (x is dead).
// R8: 512 threads + float4 loads + int2 xb writes. R15: y2/y3 are bf16
// partials (ch-major) read as short4 + convert.
// ---------------------------------------------------------------------------
template <int NADD>
__global__ __launch_bounds__(512) void k_ln(float* __restrict__ x,
        const float* __restrict__ y, const short* __restrict__ y2,
        const short* __restrict__ y3, const float* __restrict__ g,
        const float* __restrict__ bb, short* __restrict__ xb,
        const int* __restrict__ lens) {
    __shared__ float s[HN][33];
    __shared__ float red1[512], red2[512];
    __shared__ float mu[32], rs[32];
    const int b = blockIdx.y;
    const int t0 = blockIdx.x * 32;
    const int tid = threadIdx.x;
    const int len = lens[b];

    if (t0 >= len) {
        for (int i = tid; i < 32 * 48; i += 512) {
            int2 z = {0, 0};
            *(int2*)((int*)xb + ((size_t)(b * TN + t0 + i / 48)) * 96 + (i % 48) * 2) = z;
        }
        return;
    }

    // vectorized gather: 192 ch x 8 float4-groups = 1536 items, 3 per thread
    for (int i = tid; i < HN * 8; i += 512) {
        int c = i >> 3, tq = i & 7;
        size_t gi = ((size_t)b * HN + c) * TN + t0 + tq * 4;
        float4 v = *(const float4*)(x + gi);
        float4 a = *(const float4*)(y + gi);
        v.x += a.x; v.y += a.y; v.z += a.z; v.w += a.w;
        if (NADD >= 2) {
            short4 a2 = *(const short4*)(y2 + gi);
            v.x += bf2f(a2.x); v.y += bf2f(a2.y); v.z += bf2f(a2.z); v.w += bf2f(a2.w);
        }
        if (NADD >= 3) {
            short4 a3 = *(const short4*)(y3 + gi);
            v.x += bf2f(a3.x); v.y += bf2f(a3.y); v.z += bf2f(a3.z); v.w += bf2f(a3.w);
        }
        s[c][tq * 4 + 0] = v.x;
        s[c][tq * 4 + 1] = v.y;
        s[c][tq * 4 + 2] = v.z;
        s[c][tq * 4 + 3] = v.w;
    }
    __syncthreads();
    int tt = tid & 31, grp = tid >> 5;  // 16 groups x 12 channels
    float sum = 0.f, sum2 = 0.f;
    for (int c = grp * 12; c < grp * 12 + 12; ++c) {
        float v = s[c][tt];
        sum += v;
        sum2 += v * v;
    }
    red1[tid] = sum;
    red2[tid] = sum2;
    __syncthreads();
    if (tid < 32) {
        float tot = 0.f, tot2 = 0.f;
#pragma unroll
        for (int gg = 0; gg < 16; ++gg) { tot += red1[gg * 32 + tid]; tot2 += red2[gg * 32 + tid]; }
        float mean = tot / (float)HN;
        float var = tot2 / (float)HN - mean * mean;
        mu[tid] = mean;
        rs[tid] = rsqrtf(var + 1e-5f);
    }
    __syncthreads();
    // normalized x (fp32 ch-major, float4)
    for (int i = tid; i < HN * 8; i += 512) {
        int c = i >> 3, tq = i & 7;
        float gc = g[c], bc = bb[c];
        float4 o;
        o.x = (s[c][tq * 4 + 0] - mu[tq * 4 + 0]) * rs[tq * 4 + 0] * gc + bc;
        o.y = (s[c][tq * 4 + 1] - mu[tq * 4 + 1]) * rs[tq * 4 + 1] * gc + bc;
        o.z = (s[c][tq * 4 + 2] - mu[tq * 4 + 2]) * rs[tq * 4 + 2] * gc + bc;
        o.w = (s[c][tq * 4 + 3] - mu[tq * 4 + 3]) * rs[tq * 4 + 3] * gc + bc;
        *(float4*)(x + ((size_t)b * HN + c) * TN + t0 + tq * 4) = o;
    }
    // xb bf16 t-major, int2-packed (4 channels per item), masked
    for (int i = tid; i < 32 * 48; i += 512) {
        int t2 = i / 48, p2 = i % 48;
        int c0 = p2 * 4;
        float m = mu[t2], r = rs[t2];
        float v0 = (s[c0][t2] - m) * r * g[c0] + bb[c0];
        float v1 = (s[c0 + 1][t2] - m) * r * g[c0 + 1] + bb[c0 + 1];
        float v2 = (s[c0 + 2][t2] - m) * r * g[c0 + 2] + bb[c0 + 2];
        float v3 = (s[c0 + 3][t2] - m) * r * g[c0 + 3] + bb[c0 + 3];
        if (t0 + t2 >= len) { v0 = 0.f; v1 = 0.f; v2 = 0.f; v3 = 0.f; }
        int2 pk;
        pk.x = pack2(v0, v1);
        pk.y = pack2(v2, v3);
        *(int2*)((int*)xb + ((size_t)(b * TN + t0 + t2)) * 96 + p2 * 2) = pk;
    }
}

// ---------------------------------------------------------------------------
// Fused stats projection + final sampling.
// R11: 512 threads (wm x wt2 wave split). Verified.
// ---------------------------------------------------------------------------
__global__ __launch_bounds__(512) void k_statsfin(
        const short* __restrict__ W, const short* __restrict__ X,
        const float* __restrict__ bias, const float* __restrict__ x,
        const float* __restrict__ eps, const int* __restrict__ lens,
        float* __restrict__ out) {
    __shared__ short Wt[64 * GSTR];
    __shared__ short Xt[64 * GSTR];
    const int b = blockIdx.z, o0 = blockIdx.y * 64, t0 = blockIdx.x * 64;
    const int len = lens[b];
    const int tid = threadIdx.x;
    const int wave = tid >> 6, lane = tid & 63, col = lane & 15, quad = lane >> 4;
    const int wm = wave & 3, wt2 = wave >> 2;  // wm: o-frag, wt2: t-half
    const size_t S = (size_t)BN * OUTN * TN;

    if (t0 >= len) {
        for (int i = tid; i < 4096; i += 512) {
            int oo = i >> 6, tt = i & 63;
            size_t idx = ((size_t)b * OUTN + o0 + oo) * TN + t0 + tt;
            out[idx] = 0.f;
            out[S + idx] = 0.f;
            out[2 * S + idx] = 0.f;
            out[3 * S + idx] = 0.f;
        }
        if (o0 == 0 && tid < 64) out[4 * S + (size_t)b * TN + t0 + tid] = 0.f;
        return;
    }

    for (int i = tid; i < 1536; i += 512) {
        int tt = i / 24, part = i % 24;
        *(int4*)(Xt + tt * GSTR + part * 8) =
            *(const int4*)(X + ((size_t)(b * TN + t0 + tt)) * 192 + part * 8);
    }
    for (int i = tid; i < 1536; i += 512) {
        int mm = i / 24, part = i % 24;
        *(int4*)(Wt + mm * GSTR + part * 8) =
            *(const int4*)(W + ((size_t)(o0 + mm)) * 192 + part * 8);
    }
    __syncthreads();

    f32x4 am[2];
#pragma unroll
    for (int st = 0; st < 2; ++st) am[st] = (f32x4){0.f, 0.f, 0.f, 0.f};
#pragma unroll
    for (int ks = 0; ks < 6; ++ks) {
        bfrag af = *(const bfrag*)(Wt + (wm * 16 + col) * GSTR + ks * 32 + quad * 8);
#pragma unroll
        for (int st = 0; st < 2; ++st) {
            bfrag bf = *(const bfrag*)(Xt + ((wt2 * 2 + st) * 16 + col) * GSTR + ks * 32 + quad * 8);
            am[st] = __builtin_amdgcn_mfma_f32_16x16x32_bf16(af, bf, am[st], 0, 0, 0);
        }
    }
    __syncthreads();
    for (int i = tid; i < 1536; i += 512) {
        int mm = i / 24, part = i % 24;
        *(int4*)(Wt + mm * GSTR + part * 8) =
            *(const int4*)(W + ((size_t)(192 + o0 + mm)) * 192 + part * 8);
    }
    __syncthreads();

    f32x4 al[2];
#pragma unroll
    for (int st = 0; st < 2; ++st) al[st] = (f32x4){0.f, 0.f, 0.f, 0.f};
#pragma unroll
    for (int ks = 0; ks < 6; ++ks) {
        bfrag af = *(const bfrag*)(Wt + (wm * 16 + col) * GSTR + ks * 32 + quad * 8);
#pragma unroll
        for (int st = 0; st < 2; ++st) {
            bfrag bf = *(const bfrag*)(Xt + ((wt2 * 2 + st) * 16 + col) * GSTR + ks * 32 + quad * 8);
            al[st] = __builtin_amdgcn_mfma_f32_16x16x32_bf16(af, bf, al[st], 0, 0, 0);
        }
    }

    const int obase = o0 + wm * 16 + quad * 4;
    float bm[4], bl[4];
#pragma unroll
    for (int reg = 0; reg < 4; ++reg) {
        bm[reg] = bias[obase + reg];
        bl[reg] = bias[192 + obase + reg];
    }
#pragma unroll
    for (int st = 0; st < 2; ++st) {
        int t = t0 + (wt2 * 2 + st) * 16 + col;
        bool om = (t >= len);
#pragma unroll
        for (int reg = 0; reg < 4; ++reg) {
            float m = am[st][reg] + bm[reg];
            float ls = al[st][reg] + bl[reg];
            if (om) { m = 0.f; ls = 0.f; }
            size_t idx = ((size_t)b * OUTN + obase + reg) * TN + t;
            float e = eps[idx];
            out[idx] = om ? 0.f : m + e * __expf(ls);
            out[S + idx] = m;
            out[2 * S + idx] = ls;
        }
    }
    for (int i = tid; i < 4096; i += 512) {
        int oo = i >> 6, tt = i & 63;
        int t = t0 + tt;
        float mv = (t < len) ? 1.f : 0.f;
        size_t idx = ((size_t)b * OUTN + o0 + oo) * TN + t;
        out[3 * S + idx] = x[((size_t)b * HN + o0 + oo) * TN + t] * mv;
    }
    if (o0 == 0 && tid < 64)
        out[4 * S + (size_t)b * TN + t0 + tid] = (t0 + tid < len) ? 1.f : 0.f;
}

// ---------------------------------------------------------------------------
extern "C" void kernel_launch(void* const* d_in, const int* in_sizes, int n_in,
                              void* d_out, int out_size, void* d_ws, size_t ws_size,
                              hipStream_t stream) {
    const int* tok = (const int*)d_in[0];
    const int* lens = (const int*)d_in[1];
    const float* emb = (const float*)d_in[2];
    const float* qw = (const float*)d_in[3];
    const float* qb = (const float*)d_in[4];
    const float* kw = (const float*)d_in[5];
    const float* kb = (const float*)d_in[6];
    const float* vw = (const float*)d_in[7];
    const float* vb = (const float*)d_in[8];
    const float* ow = (const float*)d_in[9];
    const float* ob = (const float*)d_in[10];
    const float* relk = (const float*)d_in[11];
    const float* relv = (const float*)d_in[12];
    const float* ln1g = (const float*)d_in[13];
    const float* ln1b = (const float*)d_in[14];
    const float* f1w = (const float*)d_in[15];
    const float* f1b = (const float*)d_in[16];
    const float* f2w = (const float*)d_in[17];
    const float* f2b = (const float*)d_in[18];
    const float* ln2g = (const float*)d_in[19];
    const float* ln2b = (const float*)d_in[20];
    const float* pw = (const float*)d_in[21];
    const float* pb = (const float*)d_in[22];
    const float* eps = (const float*)d_in[23];

    const size_t BHT = (size_t)BN * HN * TN; // 1,572,864
    float* ws = (float*)d_ws;
    float* x = ws;                                   // fp32 ch-major
    float* yf = ws + BHT;                            // fp32 ch-major (f2 kg=0)
    short* s_xb = (short*)(ws + 2 * BHT);            // bf16 t-major (qkv/stats in)
    short* s_ln = (short*)(ws + 2 * BHT + BHT / 2);  // bf16 t-major (f1 in)
    short* s_q  = (short*)(ws + 3 * BHT);
    short* s_k  = (short*)(ws + 3 * BHT + BHT / 2);
    short* s_v  = (short*)(ws + 4 * BHT);
    short* p1   = (short*)(ws + 3 * BHT);  // f2 partial kg=1 bf16 (overlays s_q: dead by then)
    short* p2   = (short*)(ws + 4 * BHT);  // f2 partial kg=2 bf16 (overlays s_v: dead by then)
    short* accP = (short*)(ws + 5 * BHT);            // 4 x BHT shorts (attn partials)
    short* s_y1 = (short*)(ws + 5 * BHT);            // f1 out (B,T,FFN), after attn consumed
    short* wqkv = (short*)(ws + 7 * BHT);            // [L][576][192]
    short* wo16 = wqkv + (size_t)LN * 3 * HN * HN;
    short* wp16 = wo16 + (size_t)LN * HN * HN;
    short* wf1_16 = wp16 + (size_t)2 * OUTN * HN;
    short* wf2_16 = wf1_16 + (size_t)LN * 3 * FFNN * HN;
    float* bqkv = (float*)(wf2_16 + (size_t)LN * 3 * FFNN * HN);  // [L][576]
    float* lP = bqkv + (size_t)LN * 576;             // 4 x B x NH x T floats

    // fused weight conversion (single launch)
    {
        long total = (long)LN * 576 * 192 + LN * 576 + LN * HN * HN + 2 * OUTN * HN
                   + 2L * LN * FFNN * HN * 3;
        k_cvtall<<<dim3((unsigned)((total + 255) / 256)), 256, 0, stream>>>(
            qw, kw, vw, qb, kb, vb, ow, pw, f1w, f2w,
            wqkv, bqkv, wo16, wp16, wf1_16, wf2_16);
    }

    dim3 gemb(TN / 16, BN);             // 64 x 8 (2 blocks/CU for token gather)
    k_embed<<<gemb, 256, 0, stream>>>(tok, lens, emb, x, s_xb);

    dim3 gqkv(TN / 128, 9, BN);         // 8 x 9 x 8 (512 thr)
    dim3 gattn(TN / 128, NHN * 4, BN);  // 8 x 8 x 8 (512-thread blocks)
    dim3 gol(TN / 32, BN);              // 32 x 8 (fused oproj+merge+LN1, 512 thr)
    dim3 gf1(TN / 128, FFNN / 64, BN);  // 8 x 12 x 8 (512 thr)
    dim3 gf2(TN / 128, 9, BN);          // 8 x (3m x 3kg) x 8 (512 thr)
    dim3 gln(TN / 32, BN);              // 32 x 8 (512 thr)

    for (int i = 0; i < LN; ++i) {
        const short* qkvwi = wqkv + (size_t)i * 576 * 192;
        const float* qkvbi = bqkv + (size_t)i * 576;
        const short* owi = wo16 + (size_t)i * HN * HN;
        const short* f1wi = wf1_16 + (size_t)i * 3 * FFNN * HN;
        const short* f2wi = wf2_16 + (size_t)i * 3 * FFNN * HN;
        const float* obi = ob + (size_t)i * HN;
        const float* rki = relk + (size_t)i * 9 * KCN;
        const float* rvi = relv + (size_t)i * 9 * KCN;
        const float* l1gi = ln1g + (size_t)i * HN;
        const float* l1bi = ln1b + (size_t)i * HN;
        const float* f1bi = f1b + (size_t)i * FFNN;
        const float* f2bi = f2b + (size_t)i * HN;
        const float* l2gi = ln2g + (size_t)i * HN;
        const float* l2bi = ln2b + (size_t)i * HN;

        k_qkv2<<<gqkv, 512, 0, stream>>>(qkvwi, s_xb, qkvbi, s_q, s_k, s_v, lens);
        k_attn4<<<gattn, 512, 0, stream>>>(s_q, s_k, s_v, rki, rvi, accP, lP, lens);
        k_oln<<<gol, 512, 0, stream>>>(owi, obi, accP, lP, x, l1gi, l1bi, s_ln, lens);
        k_mgemm<3, 128, true, true, 1, 1, false><<<gf1, 512, 0, stream>>>(
            f1wi, s_ln, f1bi, s_y1, nullptr, nullptr, lens, FFNN, HN);
        k_mgemm<3, 128, false, true, 0, 3, true><<<gf2, 512, 0, stream>>>(
            f2wi, s_y1, f2bi, yf, (float*)p1, (float*)p2, lens, HN, FFNN);
        k_ln<3><<<gln, 512, 0, stream>>>(x, yf, p1, p2, l2gi, l2bi, s_xb, lens);
    }

    dim3 gsf(TN / 64, OUTN / 64, BN);   // 16 x 3 x 8 (512 thr)
    k_statsfin<<<gsf, 512, 0, stream>>>(wp16, s_xb, pb, x, eps, lens, (float*)d_out);
}

// Round 16
// 752.816 us; speedup vs baseline: 1.0211x; 1.0048x over previous
//
#include <hip/hip_runtime.h>
#include <math.h>

#define BN 8
#define TN 1024
#define HN 192
#define NHN 2
#define KCN 96
#define LN 6
#define FFNN 768
#define OUTN 192
#define QSTR 104  // kt/rbt LDS row stride in shorts: 13 granules (odd) -> conflict-free b128
#define GSTR 200  // K=192 GEMM LDS row stride (192 data + pad): 25 granules (odd)
#define M0S 12.0f // fixed softmax shift: scores are O(1); exp(s-12) safe to s~100

typedef short bfrag __attribute__((ext_vector_type(8)));
typedef float f32x4 __attribute__((ext_vector_type(4)));

__device__ __forceinline__ short f2bf(float f) {
    union { float f; unsigned u; } v; v.f = f;
    unsigned r = v.u + 0x7fffu + ((v.u >> 16) & 1u);
    return (short)(r >> 16);
}
__device__ __forceinline__ float bf2f(short s) {
    union { unsigned u; float f; } v;
    v.u = ((unsigned)(unsigned short)s) << 16;
    return v.f;
}
__device__ __forceinline__ int pack2(float a, float b) {
    return (int)(unsigned short)f2bf(a) | (((int)(unsigned short)f2bf(b)) << 16);
}

#define QSCALE 0.10206207261596575f  // 1/sqrt(96)

// ---------------------------------------------------------------------------
// Fused weight conversions (one launch).
// ---------------------------------------------------------------------------
__global__ void k_cvtall(const float* __restrict__ qw, const float* __restrict__ kw,
        const float* __restrict__ vw, const float* __restrict__ qb,
        const float* __restrict__ kb, const float* __restrict__ vb,
        const float* __restrict__ ow, const float* __restrict__ pw,
        const float* __restrict__ f1w, const float* __restrict__ f2w,
        short* __restrict__ wqkv, float* __restrict__ bqkv,
        short* __restrict__ wo16, short* __restrict__ wp16,
        short* __restrict__ wf1, short* __restrict__ wf2) {
    const int N0 = LN * 576 * 192;
    const int N1 = LN * 576;
    const int N2 = LN * HN * HN;
    const int N3 = 2 * OUTN * HN;
    const int N4 = LN * FFNN * HN * 3;
    int i = blockIdx.x * 256 + threadIdx.x;
    if (i < N0) {
        int c = i % 192, r = (i / 192) % 576, l = i / (192 * 576);
        float val, sc = 1.f;
        if (r < 192) { val = qw[((size_t)l * 192 + r) * 192 + c]; sc = QSCALE; }
        else if (r < 384) val = kw[((size_t)l * 192 + (r - 192)) * 192 + c];
        else val = vw[((size_t)l * 192 + (r - 384)) * 192 + c];
        wqkv[i] = f2bf(val * sc);
        return;
    }
    i -= N0;
    if (i < N1) {
        int r = i % 576, l = i / 576;
        bqkv[i] = (r < 192) ? qb[l * 192 + r] * QSCALE
                : (r < 384) ? kb[l * 192 + r - 192]
                            : vb[l * 192 + r - 384];
        return;
    }
    i -= N1;
    if (i < N2) { wo16[i] = f2bf(ow[i]); return; }
    i -= N2;
    if (i < N3) { wp16[i] = f2bf(pw[i]); return; }
    i -= N3;
    if (i < N4) {
        int tap = i % 3, c = (i / 3) % HN, m = (i / (3 * HN)) % FFNN, l = i / (3 * HN * FFNN);
        wf1[(((size_t)l * 3 + tap) * FFNN + m) * HN + c] = f2bf(f1w[i]);
        return;
    }
    i -= N4;
    if (i < N4) {
        int tap = i % 3, c = (i / 3) % FFNN, m = (i / (3 * FFNN)) % HN, l = i / (3 * FFNN * HN);
        wf2[(((size_t)l * 3 + tap) * HN + m) * FFNN + c] = f2bf(f2w[i]);
    }
}

// ---------------------------------------------------------------------------
// Embedding: x fp32 ch-major (B,H,T) + xb bf16 t-major (B,T,H), both masked.
// R11: 16-t tiles, grid 512 (2 blocks/CU). Verified.
// ---------------------------------------------------------------------------
__global__ __launch_bounds__(256) void k_embed(const int* __restrict__ tok,
        const int* __restrict__ lens, const float* __restrict__ emb,
        float* __restrict__ x, short* __restrict__ xb) {
    __shared__ float s[HN][17];
    const int b = blockIdx.y, t0 = blockIdx.x * 16, tid = threadIdx.x;
    const int len = lens[b];
    for (int idx = tid; idx < 16 * HN; idx += 256) {
        int tt = idx / HN, c = idx % HN;
        int t = t0 + tt;
        float v = 0.f;
        if (t < len) v = emb[tok[b * TN + t] * HN + c] * 13.856406460551018f; // sqrt(192)
        s[c][tt] = v;
    }
    __syncthreads();
    for (int idx = tid; idx < 16 * HN; idx += 256) {
        int c = idx >> 4, tt = idx & 15;
        x[((size_t)b * HN + c) * TN + t0 + tt] = s[c][tt];
    }
    for (int idx = tid; idx < 16 * 96; idx += 256) {
        int tt = idx / 96, p = idx % 96;
        ((int*)xb)[((size_t)(b * TN + t0 + tt)) * 96 + p] = pack2(s[2 * p][tt], s[2 * p + 1][tt]);
    }
}

// ---------------------------------------------------------------------------
// Fused o-proj + merge + residual + LN1, 512 threads (wm x wt), LDS-staged W,
// hoisted x residual staging. Verified (R11 form).
// ---------------------------------------------------------------------------
__global__ __launch_bounds__(512, 2) void k_oln(
        const short* __restrict__ W, const float* __restrict__ bias,
        const short* __restrict__ accP, const float* __restrict__ lPp,
        float* __restrict__ x, const float* __restrict__ g,
        const float* __restrict__ bb, short* __restrict__ xb,
        const int* __restrict__ lens) {
    __shared__ short Wt[192 * GSTR];   // 76.8 KB
    __shared__ short Xt[32 * GSTR];    // 12.8 KB
    __shared__ float s_out[HN][33];    // 25.3 KB (x stage, then LN output)
    __shared__ float linv[64];
    __shared__ float red1[32 * 16], red2[32 * 16];
    __shared__ float mu[32], rs[32];
    const int b = blockIdx.y, t0 = blockIdx.x * 32;
    const int len = lens[b];
    const int tid = threadIdx.x;
    const int wave = tid >> 6, lane = tid & 63, col = lane & 15, quad = lane >> 4;
    const int wm = wave & 3, wt = wave >> 2;   // wm: m-frag group, wt: t-strip

    if (t0 >= len) {
        for (int idx = tid; idx < 32 * 96; idx += 512)
            ((int*)xb)[((size_t)(b * TN + t0 + idx / 96)) * 96 + idx % 96] = 0;
        return;
    }

    if (tid < 64) {
        int tt = tid & 31, h = tid >> 5;
        float l = 0.f;
#pragma unroll
        for (int sh = 0; sh < 4; ++sh)
            l += lPp[(((size_t)sh * BN + b) * NHN + h) * TN + t0 + tt];
        linv[tid] = (l > 0.f) ? 1.f / l : 0.f;
    }
    // stage W (192 x 24 granules)
    for (int i = tid; i < 4608; i += 512) {
        int mm = i / 24, part = i % 24;
        *(int4*)(Wt + mm * GSTR + part * 8) =
            *(const int4*)(W + ((size_t)mm) * 192 + part * 8);
    }
    // stage x tile for residual add (hoisted: hides under merge+MFMA)
    for (int i = tid; i < 6144; i += 512) {
        int c = i >> 5, tt = i & 31;
        s_out[c][tt] = x[((size_t)b * HN + c) * TN + t0 + tt];
    }
    __syncthreads();  // linv ready for merge; W/s_out published
    // merge accP -> Xt (32 x 24 granules), once per t
    const size_t HSq = (size_t)BN * TN * HN;
    for (int i = tid; i < 768; i += 512) {
        int tt = i / 24, part = i % 24;
        const size_t base = ((size_t)(b * TN + t0 + tt)) * 192 + part * 8;
        float a[8];
#pragma unroll
        for (int c = 0; c < 8; ++c) a[c] = 0.f;
#pragma unroll
        for (int sh = 0; sh < 4; ++sh) {
            int4 v = *(const int4*)(accP + sh * HSq + base);
            const short* sv = (const short*)&v;
#pragma unroll
            for (int c = 0; c < 8; ++c) a[c] += bf2f(sv[c]);
        }
        float li = linv[(part >= 12 ? 32 : 0) + tt];
        int4 o;
        int* oi = (int*)&o;
#pragma unroll
        for (int c = 0; c < 4; ++c) oi[c] = pack2(a[2 * c] * li, a[2 * c + 1] * li);
        *(int4*)(Xt + tt * GSTR + part * 8) = o;
    }
    __syncthreads();

    f32x4 acc[3];
#pragma unroll
    for (int mf3 = 0; mf3 < 3; ++mf3) acc[mf3] = (f32x4){0.f, 0.f, 0.f, 0.f};
#pragma unroll
    for (int ks = 0; ks < 6; ++ks) {
        bfrag bfx = *(const bfrag*)(Xt + (wt * 16 + col) * GSTR + ks * 32 + quad * 8);
#pragma unroll
        for (int mf3 = 0; mf3 < 3; ++mf3) {
            int mf = mf3 * 4 + wm;
            bfrag af = *(const bfrag*)(Wt + (mf * 16 + col) * GSTR + ks * 32 + quad * 8);
            acc[mf3] = __builtin_amdgcn_mfma_f32_16x16x32_bf16(af, bfx, acc[mf3], 0, 0, 0);
        }
    }

    // residual add + per-t partial stats (each thread owns 12 channels at tcol)
    float bsv[3][4];
#pragma unroll
    for (int mf3 = 0; mf3 < 3; ++mf3)
#pragma unroll
        for (int reg = 0; reg < 4; ++reg)
            bsv[mf3][reg] = bias[(mf3 * 4 + wm) * 16 + quad * 4 + reg];
    {
        const int tcol = wt * 16 + col;
        float s1 = 0.f, s2 = 0.f;
#pragma unroll
        for (int mf3 = 0; mf3 < 3; ++mf3) {
#pragma unroll
            for (int reg = 0; reg < 4; ++reg) {
                int row = (mf3 * 4 + wm) * 16 + quad * 4 + reg;
                float v = acc[mf3][reg] + bsv[mf3][reg] + s_out[row][tcol];
                acc[mf3][reg] = v;
                s1 += v;
                s2 += v * v;
            }
        }
        red1[tcol * 16 + (wm * 4 + quad)] = s1;
        red2[tcol * 16 + (wm * 4 + quad)] = s2;
    }
    __syncthreads();
    if (tid < 32) {
        float tot = 0.f, tot2 = 0.f;
#pragma unroll
        for (int gg = 0; gg < 16; ++gg) {
            tot += red1[tid * 16 + gg];
            tot2 += red2[tid * 16 + gg];
        }
        float mean = tot / (float)HN;
        float var = tot2 / (float)HN - mean * mean;
        mu[tid] = mean;
        rs[tid] = rsqrtf(var + 1e-5f);
    }
    __syncthreads();
    // normalize into s_out (each thread writes its own 12 cells)
    {
        const int tcol = wt * 16 + col;
#pragma unroll
        for (int mf3 = 0; mf3 < 3; ++mf3) {
#pragma unroll
            for (int reg = 0; reg < 4; ++reg) {
                int row = (mf3 * 4 + wm) * 16 + quad * 4 + reg;
                s_out[row][tcol] = (acc[mf3][reg] - mu[tcol]) * rs[tcol] * g[row] + bb[row];
            }
        }
    }
    __syncthreads();
    // coalesced epilogue: x (fp32 ch-major) + xb (bf16 t-major, masked)
    for (int i = tid; i < 6144; i += 512) {
        int c = i >> 5, tt = i & 31;
        x[((size_t)b * HN + c) * TN + t0 + tt] = s_out[c][tt];
    }
    for (int idx = tid; idx < 32 * 96; idx += 512) {
        int t2 = idx / 96, p = idx % 96;
        float v0 = s_out[2 * p][t2], v1 = s_out[2 * p + 1][t2];
        if (t0 + t2 >= len) { v0 = 0.f; v1 = 0.f; }
        ((int*)xb)[((size_t)(b * TN + t0 + t2)) * 96 + p] = pack2(v0, v1);
    }
}

// ---------------------------------------------------------------------------
// R9: fused QKV projection, 128-wide t-tiles, 512 threads (8 waves: wm x wt2).
// Verified. Masking semantics unchanged.
// ---------------------------------------------------------------------------
__global__ __launch_bounds__(512) void k_qkv2(
        const short* __restrict__ W, const short* __restrict__ X,
        const float* __restrict__ bias, short* __restrict__ qo,
        short* __restrict__ ko, short* __restrict__ vo,
        const int* __restrict__ lens) {
    __shared__ short Wt[64 * GSTR];    // 25.6 KB
    __shared__ short Xt[128 * GSTR];   // 51.2 KB
    const int b = blockIdx.z, m0 = blockIdx.y * 64, t0 = blockIdx.x * 128;
    const int len = lens[b];
    const int tid = threadIdx.x;
    const int wave = tid >> 6, lane = tid & 63, col = lane & 15, quad = lane >> 4;
    const int wm = wave & 3, wt2 = wave >> 2;  // wm: m-frag, wt2: t-half
    const int proj = m0 / 192;           // block-uniform: 0=q 1=k 2=v
    const int mbase = m0 + wm * 16 + quad * 4;
    const int mloc = mbase - proj * 192;

    if (t0 >= len) {
        if (proj == 1) return;
#pragma unroll
        for (int st = 0; st < 4; ++st) {
            int t = t0 + (wt2 * 4 + st) * 16 + col;
            if (proj == 0) {
                int2 z = {0, 0};
                *(int2*)(qo + ((size_t)(b * TN + t)) * 192 + mloc) = z;
            } else {
#pragma unroll
                for (int reg = 0; reg < 4; ++reg)
                    vo[((size_t)b * 192 + mloc + reg) * TN + t] = 0;
            }
        }
        return;
    }

    for (int i = tid; i < 1536; i += 512) {
        int mm = i / 24, part = i % 24;
        *(int4*)(Wt + mm * GSTR + part * 8) =
            *(const int4*)(W + ((size_t)(m0 + mm)) * 192 + part * 8);
    }
    for (int i = tid; i < 3072; i += 512) {
        int tt = i / 24, part = i % 24;
        *(int4*)(Xt + tt * GSTR + part * 8) =
            *(const int4*)(X + ((size_t)(b * TN + t0 + tt)) * 192 + part * 8);
    }
    __syncthreads();

    f32x4 acc[4];
#pragma unroll
    for (int st = 0; st < 4; ++st) acc[st] = (f32x4){0.f, 0.f, 0.f, 0.f};
#pragma unroll
    for (int ks = 0; ks < 6; ++ks) {
        bfrag af = *(const bfrag*)(Wt + (wm * 16 + col) * GSTR + ks * 32 + quad * 8);
#pragma unroll
        for (int st = 0; st < 4; ++st) {
            bfrag bf = *(const bfrag*)(Xt + ((wt2 * 4 + st) * 16 + col) * GSTR + ks * 32 + quad * 8);
            acc[st] = __builtin_amdgcn_mfma_f32_16x16x32_bf16(af, bf, acc[st], 0, 0, 0);
        }
    }

    float bs[4];
#pragma unroll
    for (int reg = 0; reg < 4; ++reg) bs[reg] = bias[mbase + reg];
#pragma unroll
    for (int st = 0; st < 4; ++st) {
        int t = t0 + (wt2 * 4 + st) * 16 + col;
        float v[4];
#pragma unroll
        for (int reg = 0; reg < 4; ++reg) v[reg] = acc[st][reg] + bs[reg];
        if (proj < 2) {
            short* dst = (proj == 0) ? qo : ko;
            int2 pk;
            pk.x = pack2(v[0], v[1]);
            pk.y = pack2(v[2], v[3]);
            *(int2*)(dst + ((size_t)(b * TN + t)) * 192 + mloc) = pk;
        } else {
#pragma unroll
            for (int reg = 0; reg < 4; ++reg)
                vo[((size_t)b * 192 + mloc + reg) * TN + t] = f2bf(v[reg]);
        }
    }
}

// ---------------------------------------------------------------------------
// MFMA bf16 conv (f1, f2). Masked t-tiles: zero-fill output, skip compute.
// R10: 512 threads (wm x wt2). Verified.
// R15/R16: PBF flag -- ALL OUTK==0 outputs written bf16 (kg=0 incl. bias).
// Partials feed only the ln2 sum; GEMM inputs already bf16-quantized.
// ---------------------------------------------------------------------------
template <int TAPS, int TT, bool RELU, bool MASK_OUT, int OUTK, int KSPLIT, bool PBF>
__global__ __launch_bounds__(512) void k_mgemm(
        const short* __restrict__ W, const short* __restrict__ X,
        const float* __restrict__ bias, void* __restrict__ Yv,
        float* __restrict__ Yv2, float* __restrict__ Yv3,
        const int* __restrict__ lens, int M, int Cin) {
    constexpr int P = (TAPS - 1) / 2;
    constexpr int NST = TT / 16;
    constexpr int NST2 = NST / 2;      // per-wave t-frags
    __shared__ short Wt[TAPS][64][72];
    __shared__ short Xt[TT + 2 * P][72];

    const int b = blockIdx.z;
    const int mtiles = gridDim.y / KSPLIT;
    const int kg = blockIdx.y / mtiles;
    const int m0 = (blockIdx.y % mtiles) * 64;
    const int t0 = blockIdx.x * TT;
    const int len = lens[b];
    const int tid = threadIdx.x;
    const int wave = tid >> 6;
    const int lane = tid & 63;
    const int col = lane & 15;
    const int quad = lane >> 4;
    const int wm = wave & 3, wt2 = wave >> 2;  // wm: m-frag, wt2: t-half
    const int mbase = m0 + wm * 16 + quad * 4;

    if (MASK_OUT && t0 >= len) {
#pragma unroll
        for (int st = 0; st < NST2; ++st) {
            int t = t0 + (wt2 * NST2 + st) * 16 + col;
            if (OUTK == 0) {
                if (PBF) {
                    short* dstp = (KSPLIT > 1)
                        ? (kg == 0 ? (short*)Yv : (short*)(kg == 1 ? Yv2 : Yv3))
                        : (short*)Yv;
#pragma unroll
                    for (int reg = 0; reg < 4; ++reg)
                        dstp[((size_t)b * M + mbase + reg) * TN + t] = 0;
                } else {
                    float* dst = (KSPLIT > 1) ? (kg == 0 ? (float*)Yv : (kg == 1 ? Yv2 : Yv3))
                                              : (float*)Yv;
#pragma unroll
                    for (int reg = 0; reg < 4; ++reg)
                        dst[((size_t)b * M + mbase + reg) * TN + t] = 0.f;
                }
            } else {
                int2 z = {0, 0};
                *(int2*)((short*)Yv + ((size_t)(b * TN + t)) * M + mbase) = z;
            }
        }
        return;
    }

    f32x4 acc[NST2];
#pragma unroll
    for (int st = 0; st < NST2; ++st) acc[st] = (f32x4){0.f, 0.f, 0.f, 0.f};

    const int cspan = Cin / KSPLIT;
    const int cbeg = kg * cspan;
    const int cend = cbeg + cspan;
    for (int c0 = cbeg; c0 < cend; c0 += 64) {
        __syncthreads();
        for (int i = tid; i < TAPS * 64 * 8; i += 512) {
            int tap = i / (64 * 8);
            int mm = (i / 8) & 63;
            int part = i & 7;
            *(int4*)(&Wt[tap][mm][part * 8]) =
                *(const int4*)(W + ((size_t)tap * M + m0 + mm) * Cin + c0 + part * 8);
        }
        for (int i = tid; i < (TT + 2 * P) * 8; i += 512) {
            int tt = i >> 3;
            int part = i & 7;
            int t = t0 + tt - P;
            int4 v = {0, 0, 0, 0};
            if (t >= 0 && t < TN)
                v = *(const int4*)(X + ((size_t)b * TN + t) * Cin + c0 + part * 8);
            *(int4*)(&Xt[tt][part * 8]) = v;
        }
        __syncthreads();
#pragma unroll
        for (int ks = 0; ks < 2; ++ks) {
#pragma unroll
            for (int tap = 0; tap < TAPS; ++tap) {
                bfrag af = *(const bfrag*)(&Wt[tap][wm * 16 + col][ks * 32 + quad * 8]);
#pragma unroll
                for (int st = 0; st < NST2; ++st) {
                    bfrag bf = *(const bfrag*)(&Xt[(wt2 * NST2 + st) * 16 + col + tap][ks * 32 + quad * 8]);
                    acc[st] = __builtin_amdgcn_mfma_f32_16x16x32_bf16(af, bf, acc[st], 0, 0, 0);
                }
            }
        }
    }

    float bs[4];
#pragma unroll
    for (int reg = 0; reg < 4; ++reg)
        bs[reg] = (KSPLIT > 1 && kg) ? 0.f : bias[mbase + reg];
#pragma unroll
    for (int st = 0; st < NST2; ++st) {
        int t = t0 + (wt2 * NST2 + st) * 16 + col;
        bool om = MASK_OUT && (t >= len);
        float v[4];
#pragma unroll
        for (int reg = 0; reg < 4; ++reg) {
            float u = acc[st][reg] + bs[reg];
            if (RELU) u = fmaxf(u, 0.f);
            if (om) u = 0.f;
            v[reg] = u;
        }
        if (OUTK == 0) {
            if (PBF) {
                short* dstp = (KSPLIT > 1)
                    ? (kg == 0 ? (short*)Yv : (short*)(kg == 1 ? Yv2 : Yv3))
                    : (short*)Yv;
#pragma unroll
                for (int reg = 0; reg < 4; ++reg)
                    dstp[((size_t)b * M + mbase + reg) * TN + t] = f2bf(v[reg]);
            } else {
                float* dst = (KSPLIT > 1) ? (kg == 0 ? (float*)Yv : (kg == 1 ? Yv2 : Yv3))
                                          : (float*)Yv;
#pragma unroll
                for (int reg = 0; reg < 4; ++reg)
                    dst[((size_t)b * M + mbase + reg) * TN + t] = v[reg];
            }
        } else {
            int2 pk;
            pk.x = pack2(v[0], v[1]);
            pk.y = pack2(v[2], v[3]);
            *(int2*)((short*)Yv + ((size_t)(b * TN + t)) * M + mbase) = pk;
        }
    }
}

// ---------------------------------------------------------------------------
// MFMA bf16 flash attention, partial-sum formulation.
// Masked q-tiles: write lP=0 (merge linv=0 kills stale accP) and return.
// sband stores p (not v) -> epilogue has no exp. NO register prefetch here:
// it spills under the 128-VGPR launch_bounds cap (R2: +19us).
// ---------------------------------------------------------------------------
__global__ __launch_bounds__(512, 4) void k_attn4(
        const short* __restrict__ Q, const short* __restrict__ K,
        const short* __restrict__ V, const float* __restrict__ relk,
        const float* __restrict__ relv, short* __restrict__ accP,
        float* __restrict__ lP, const int* __restrict__ lens) {
    __shared__ short kt[64 * QSTR];
    __shared__ short vt[96 * 72];
    __shared__ short Pt[128 * 72];
    __shared__ short rbt[16 * QSTR];   // relk as bf16 B-tile (rows 9..15 zero)
    __shared__ float rels[128 * 12];
    __shared__ float sband[128 * 12];  // stores p (post-mask softmax numerator)
    __shared__ float rvs[9 * 96];

    const int b = blockIdx.z;
    const int h = blockIdx.y >> 2, sh = blockIdx.y & 3;
    const int t0 = blockIdx.x * 128;
    const int len = lens[b];
    const int tid = threadIdx.x;
    const int w = tid >> 6;
    const int lane = tid & 63;
    const int col = lane & 15;
    const int quad = lane >> 4;

    if (t0 >= len) {
        if (tid < 128)
            lP[(((size_t)sh * BN + b) * NHN + h) * TN + t0 + tid] = 0.f;
        return;
    }

    const short* Qb = Q + ((size_t)b * TN + t0) * HN + h * KCN;
    const short* Kb = K + ((size_t)b * TN + sh * 256) * HN + h * KCN;
    const short* Vb = V + ((size_t)b * HN + h * KCN) * TN + sh * 256;

    bfrag qf[3];
#pragma unroll
    for (int ks = 0; ks < 3; ++ks)
        qf[ks] = *(const bfrag*)(Qb + (size_t)(w * 16 + col) * HN + ks * 32 + quad * 8);

    for (int i = tid; i < 9 * 96; i += 512) rvs[i] = relv[i];
    for (int i = tid; i < 16 * 96; i += 512) {
        int r = i / 96, c = i % 96;
        rbt[r * QSTR + c] = (r < 9) ? f2bf(relk[r * 96 + c]) : (short)0;
    }
    for (int i = tid; i < 128 * 12; i += 512) sband[i] = 0.f;
    __syncthreads();

    {
        f32x4 rc = (f32x4){0.f, 0.f, 0.f, 0.f};
#pragma unroll
        for (int ks = 0; ks < 3; ++ks) {
            bfrag bf = *(const bfrag*)(rbt + col * QSTR + ks * 32 + quad * 8);
            rc = __builtin_amdgcn_mfma_f32_16x16x32_bf16(qf[ks], bf, rc, 0, 0, 0);
        }
        if (col < 12) {
#pragma unroll
            for (int reg = 0; reg < 4; ++reg)
                rels[(w * 16 + quad * 4 + reg) * 12 + col] = rc[reg];
        }
    }

    float lsum[4];
    f32x4 accv[6];
#pragma unroll
    for (int r = 0; r < 4; ++r) lsum[r] = 0.f;
#pragma unroll
    for (int n = 0; n < 6; ++n) accv[n] = (f32x4){0.f, 0.f, 0.f, 0.f};

    const int rem = len - sh * 256;
    const int nj = (rem <= 0) ? 0 : ((rem >= 256) ? 4 : ((rem + 63) >> 6));

    for (int j = 0; j < nj; ++j) {
        const int s0g = sh * 256 + j * 64;
        __syncthreads();
        for (int i = tid; i < 768; i += 512) {
            int row = i / 12, part = i % 12;
            *(int4*)(kt + row * QSTR + part * 8) =
                *(const int4*)(Kb + ((size_t)(j * 64 + row)) * HN + part * 8);
        }
        for (int i = tid; i < 768; i += 512) {
            int c = i >> 3, part = i & 7;
            *(int4*)(vt + c * 72 + part * 8) =
                *(const int4*)(Vb + (size_t)c * TN + j * 64 + part * 8);
        }
        __syncthreads();

        f32x4 sacc[4];
#pragma unroll
        for (int st = 0; st < 4; ++st) sacc[st] = (f32x4){0.f, 0.f, 0.f, 0.f};
#pragma unroll
        for (int ks = 0; ks < 3; ++ks) {
#pragma unroll
            for (int st = 0; st < 4; ++st) {
                bfrag bf = *(const bfrag*)(kt + (st * 16 + col) * QSTR + ks * 32 + quad * 8);
                sacc[st] = __builtin_amdgcn_mfma_f32_16x16x32_bf16(qf[ks], bf, sacc[st], 0, 0, 0);
            }
        }

#pragma unroll
        for (int reg = 0; reg < 4; ++reg) {
            const int lq = w * 16 + quad * 4 + reg;
            const int qg = t0 + lq;
#pragma unroll
            for (int st = 0; st < 4; ++st) {
                int sg = s0g + st * 16 + col;
                float v = sacc[st][reg];
                int d = sg - qg + 4;
                bool inb = (d >= 0) && (d <= 8);
                if (inb) v += rels[lq * 12 + d];
                if (sg >= len) v = -1e4f;
                float p = __expf(v - M0S);
                if (inb) sband[lq * 12 + d] = p;
                lsum[reg] += p;
                Pt[lq * 72 + st * 16 + col] = f2bf(p);
            }
        }
#pragma unroll
        for (int ks = 0; ks < 2; ++ks) {
            bfrag af = *(const bfrag*)(Pt + (w * 16 + col) * 72 + ks * 32 + quad * 8);
#pragma unroll
            for (int nt = 0; nt < 6; ++nt) {
                bfrag bf = *(const bfrag*)(vt + (nt * 16 + col) * 72 + ks * 32 + quad * 8);
                accv[nt] = __builtin_amdgcn_mfma_f32_16x16x32_bf16(af, bf, accv[nt], 0, 0, 0);
            }
        }
    }

#pragma unroll
    for (int reg = 0; reg < 4; ++reg) {
        lsum[reg] += __shfl_xor(lsum[reg], 1);
        lsum[reg] += __shfl_xor(lsum[reg], 2);
        lsum[reg] += __shfl_xor(lsum[reg], 4);
        lsum[reg] += __shfl_xor(lsum[reg], 8);
    }
    __syncthreads();

    short* aout = accP + (size_t)sh * BN * TN * HN;
#pragma unroll
    for (int reg = 0; reg < 4; ++reg) {
        const int lq = w * 16 + quad * 4 + reg;
        const int qg = t0 + lq;
        float pb[9];
#pragma unroll
        for (int d = 0; d < 9; ++d)
            pb[d] = sband[lq * 12 + d];
#pragma unroll
        for (int nt = 0; nt < 6; ++nt) {
            int c = nt * 16 + col;
            float r = accv[nt][reg];
#pragma unroll
            for (int d = 0; d < 9; ++d) r += pb[d] * rvs[d * 96 + c];
            aout[((size_t)(b * TN + qg)) * HN + h * KCN + c] = f2bf(r);
        }
        if (col == 0)
            lP[(((size_t)sh * BN + b) * NHN + h) * TN + qg] = lsum[reg];
    }
}

// ---------------------------------------------------------------------------
// Residual + LayerNorm: x = LN(x + y [+ y2 [+ y3]])*g + b, fp32 in-place;
// masked bf16 t-major copy xb. R8: 512 threads + vectorized loads.
// R15/R16: y, y2, y3 are bf16 partials (ch-major) read as short4 + convert.
// ---------------------------------------------------------------------------
template <int NADD>
__global__ __launch_bounds__(512) void k_ln(float* __restrict__ x,
        const short* __restrict__ y, const short* __restrict__ y2,
        const short* __restrict__ y3, const float* __restrict__ g,
        const float* __restrict__ bb, short* __restrict__ xb,
        const int* __restrict__ lens) {
    __shared__ float s[HN][33];
    __shared__ float red1[512], red2[512];
    __shared__ float mu[32], rs[32];
    const int b = blockIdx.y;
    const int t0 = blockIdx.x * 32;
    const int tid = threadIdx.x;
    const int len = lens[b];

    if (t0 >= len) {
        for (int i = tid; i < 32 * 48; i += 512) {
            int2 z = {0, 0};
            *(int2*)((int*)xb + ((size_t)(b * TN + t0 + i / 48)) * 96 + (i % 48) * 2) = z;
        }
        return;
    }

    // vectorized gather: 192 ch x 8 groups of 4 t = 1536 items, 3 per thread
    for (int i = tid; i < HN * 8; i += 512) {
        int c = i >> 3, tq = i & 7;
        size_t gi = ((size_t)b * HN + c) * TN + t0 + tq * 4;
        float4 v = *(const float4*)(x + gi);
        short4 a = *(const short4*)(y + gi);
        v.x += bf2f(a.x); v.y += bf2f(a.y); v.z += bf2f(a.z); v.w += bf2f(a.w);
        if (NADD >= 2) {
            short4 a2 = *(const short4*)(y2 + gi);
            v.x += bf2f(a2.x); v.y += bf2f(a2.y); v.z += bf2f(a2.z); v.w += bf2f(a2.w);
        }
        if (NADD >= 3) {
            short4 a3 = *(const short4*)(y3 + gi);
            v.x += bf2f(a3.x); v.y += bf2f(a3.y); v.z += bf2f(a3.z); v.w += bf2f(a3.w);
        }
        s[c][tq * 4 + 0] = v.x;
        s[c][tq * 4 + 1] = v.y;
        s[c][tq * 4 + 2] = v.z;
        s[c][tq * 4 + 3] = v.w;
    }
    __syncthreads();
    int tt = tid & 31, grp = tid >> 5;  // 16 groups x 12 channels
    float sum = 0.f, sum2 = 0.f;
    for (int c = grp * 12; c < grp * 12 + 12; ++c) {
        float v = s[c][tt];
        sum += v;
        sum2 += v * v;
    }
    red1[tid] = sum;
    red2[tid] = sum2;
    __syncthreads();
    if (tid < 32) {
        float tot = 0.f, tot2 = 0.f;
#pragma unroll
        for (int gg = 0; gg < 16; ++gg) { tot += red1[gg * 32 + tid]; tot2 += red2[gg * 32 + tid]; }
        float mean = tot / (float)HN;
        float var = tot2 / (float)HN - mean * mean;
        mu[tid] = mean;
        rs[tid] = rsqrtf(var + 1e-5f);
    }
    __syncthreads();
    // normalized x (fp32 ch-major, float4)
    for (int i = tid; i < HN * 8; i += 512) {
        int c = i >> 3, tq = i & 7;
        float gc = g[c], bc = bb[c];
        float4 o;
        o.x = (s[c][tq * 4 + 0] - mu[tq * 4 + 0]) * rs[tq * 4 + 0] * gc + bc;
        o.y = (s[c][tq * 4 + 1] - mu[tq * 4 + 1]) * rs[tq * 4 + 1] * gc + bc;
        o.z = (s[c][tq * 4 + 2] - mu[tq * 4 + 2]) * rs[tq * 4 + 2] * gc + bc;
        o.w = (s[c][tq * 4 + 3] - mu[tq * 4 + 3]) * rs[tq * 4 + 3] * gc + bc;
        *(float4*)(x + ((size_t)b * HN + c) * TN + t0 + tq * 4) = o;
    }
    // xb bf16 t-major, int2-packed (4 channels per item), masked
    for (int i = tid; i < 32 * 48; i += 512) {
        int t2 = i / 48, p2 = i % 48;
        int c0 = p2 * 4;
        float m = mu[t2], r = rs[t2];
        float v0 = (s[c0][t2] - m) * r * g[c0] + bb[c0];
        float v1 = (s[c0 + 1][t2] - m) * r * g[c0 + 1] + bb[c0 + 1];
        float v2 = (s[c0 + 2][t2] - m) * r * g[c0 + 2] + bb[c0 + 2];
        float v3 = (s[c0 + 3][t2] - m) * r * g[c0 + 3] + bb[c0 + 3];
        if (t0 + t2 >= len) { v0 = 0.f; v1 = 0.f; v2 = 0.f; v3 = 0.f; }
        int2 pk;
        pk.x = pack2(v0, v1);
        pk.y = pack2(v2, v3);
        *(int2*)((int*)xb + ((size_t)(b * TN + t0 + t2)) * 96 + p2 * 2) = pk;
    }
}

// ---------------------------------------------------------------------------
// Fused stats projection + final sampling.
// R11: 512 threads (wm x wt2 wave split). Verified.
// ---------------------------------------------------------------------------
__global__ __launch_bounds__(512) void k_statsfin(
        const short* __restrict__ W, const short* __restrict__ X,
        const float* __restrict__ bias, const float* __restrict__ x,
        const float* __restrict__ eps, const int* __restrict__ lens,
        float* __restrict__ out) {
    __shared__ short Wt[64 * GSTR];
    __shared__ short Xt[64 * GSTR];
    const int b = blockIdx.z, o0 = blockIdx.y * 64, t0 = blockIdx.x * 64;
    const int len = lens[b];
    const int tid = threadIdx.x;
    const int wave = tid >> 6, lane = tid & 63, col = lane & 15, quad = lane >> 4;
    const int wm = wave & 3, wt2 = wave >> 2;  // wm: o-frag, wt2: t-half
    const size_t S = (size_t)BN * OUTN * TN;

    if (t0 >= len) {
        for (int i = tid; i < 4096; i += 512) {
            int oo = i >> 6, tt = i & 63;
            size_t idx = ((size_t)b * OUTN + o0 + oo) * TN + t0 + tt;
            out[idx] = 0.f;
            out[S + idx] = 0.f;
            out[2 * S + idx] = 0.f;
            out[3 * S + idx] = 0.f;
        }
        if (o0 == 0 && tid < 64) out[4 * S + (size_t)b * TN + t0 + tid] = 0.f;
        return;
    }

    for (int i = tid; i < 1536; i += 512) {
        int tt = i / 24, part = i % 24;
        *(int4*)(Xt + tt * GSTR + part * 8) =
            *(const int4*)(X + ((size_t)(b * TN + t0 + tt)) * 192 + part * 8);
    }
    for (int i = tid; i < 1536; i += 512) {
        int mm = i / 24, part = i % 24;
        *(int4*)(Wt + mm * GSTR + part * 8) =
            *(const int4*)(W + ((size_t)(o0 + mm)) * 192 + part * 8);
    }
    __syncthreads();

    f32x4 am[2];
#pragma unroll
    for (int st = 0; st < 2; ++st) am[st] = (f32x4){0.f, 0.f, 0.f, 0.f};
#pragma unroll
    for (int ks = 0; ks < 6; ++ks) {
        bfrag af = *(const bfrag*)(Wt + (wm * 16 + col) * GSTR + ks * 32 + quad * 8);
#pragma unroll
        for (int st = 0; st < 2; ++st) {
            bfrag bf = *(const bfrag*)(Xt + ((wt2 * 2 + st) * 16 + col) * GSTR + ks * 32 + quad * 8);
            am[st] = __builtin_amdgcn_mfma_f32_16x16x32_bf16(af, bf, am[st], 0, 0, 0);
        }
    }
    __syncthreads();
    for (int i = tid; i < 1536; i += 512) {
        int mm = i / 24, part = i % 24;
        *(int4*)(Wt + mm * GSTR + part * 8) =
            *(const int4*)(W + ((size_t)(192 + o0 + mm)) * 192 + part * 8);
    }
    __syncthreads();

    f32x4 al[2];
#pragma unroll
    for (int st = 0; st < 2; ++st) al[st] = (f32x4){0.f, 0.f, 0.f, 0.f};
#pragma unroll
    for (int ks = 0; ks < 6; ++ks) {
        bfrag af = *(const bfrag*)(Wt + (wm * 16 + col) * GSTR + ks * 32 + quad * 8);
#pragma unroll
        for (int st = 0; st < 2; ++st) {
            bfrag bf = *(const bfrag*)(Xt + ((wt2 * 2 + st) * 16 + col) * GSTR + ks * 32 + quad * 8);
            al[st] = __builtin_amdgcn_mfma_f32_16x16x32_bf16(af, bf, al[st], 0, 0, 0);
        }
    }

    const int obase = o0 + wm * 16 + quad * 4;
    float bm[4], bl[4];
#pragma unroll
    for (int reg = 0; reg < 4; ++reg) {
        bm[reg] = bias[obase + reg];
        bl[reg] = bias[192 + obase + reg];
    }
#pragma unroll
    for (int st = 0; st < 2; ++st) {
        int t = t0 + (wt2 * 2 + st) * 16 + col;
        bool om = (t >= len);
#pragma unroll
        for (int reg = 0; reg < 4; ++reg) {
            float m = am[st][reg] + bm[reg];
            float ls = al[st][reg] + bl[reg];
            if (om) { m = 0.f; ls = 0.f; }
            size_t idx = ((size_t)b * OUTN + obase + reg) * TN + t;
            float e = eps[idx];
            out[idx] = om ? 0.f : m + e * __expf(ls);
            out[S + idx] = m;
            out[2 * S + idx] = ls;
        }
    }
    for (int i = tid; i < 4096; i += 512) {
        int oo = i >> 6, tt = i & 63;
        int t = t0 + tt;
        float mv = (t < len) ? 1.f : 0.f;
        size_t idx = ((size_t)b * OUTN + o0 + oo) * TN + t;
        out[3 * S + idx] = x[((size_t)b * HN + o0 + oo) * TN + t] * mv;
    }
    if (o0 == 0 && tid < 64)
        out[4 * S + (size_t)b * TN + t0 + tid] = (t0 + tid < len) ? 1.f : 0.f;
}

// ---------------------------------------------------------------------------
extern "C" void kernel_launch(void* const* d_in, const int* in_sizes, int n_in,
                              void* d_out, int out_size, void* d_ws, size_t ws_size,
                              hipStream_t stream) {
    const int* tok = (const int*)d_in[0];
    const int* lens = (const int*)d_in[1];
    const float* emb = (const float*)d_in[2];
    const float* qw = (const float*)d_in[3];
    const float* qb = (const float*)d_in[4];
    const float* kw = (const float*)d_in[5];
    const float* kb = (const float*)d_in[6];
    const float* vw = (const float*)d_in[7];
    const float* vb = (const float*)d_in[8];
    const float* ow = (const float*)d_in[9];
    const float* ob = (const float*)d_in[10];
    const float* relk = (const float*)d_in[11];
    const float* relv = (const float*)d_in[12];
    const float* ln1g = (const float*)d_in[13];
    const float* ln1b = (const float*)d_in[14];
    const float* f1w = (const float*)d_in[15];
    const float* f1b = (const float*)d_in[16];
    const float* f2w = (const float*)d_in[17];
    const float* f2b = (const float*)d_in[18];
    const float* ln2g = (const float*)d_in[19];
    const float* ln2b = (const float*)d_in[20];
    const float* pw = (const float*)d_in[21];
    const float* pb = (const float*)d_in[22];
    const float* eps = (const float*)d_in[23];

    const size_t BHT = (size_t)BN * HN * TN; // 1,572,864
    float* ws = (float*)d_ws;
    float* x = ws;                                   // fp32 ch-major
    short* s_yf = (short*)(ws + BHT);                // f2 kg=0 out, bf16 ch-major (R16)
    short* s_xb = (short*)(ws + 2 * BHT);            // bf16 t-major (qkv/stats in)
    short* s_ln = (short*)(ws + 2 * BHT + BHT / 2);  // bf16 t-major (f1 in)
    short* s_q  = (short*)(ws + 3 * BHT);
    short* s_k  = (short*)(ws + 3 * BHT + BHT / 2);
    short* s_v  = (short*)(ws + 4 * BHT);
    short* p1   = (short*)(ws + 3 * BHT);  // f2 partial kg=1 bf16 (overlays s_q: dead by then)
    short* p2   = (short*)(ws + 4 * BHT);  // f2 partial kg=2 bf16 (overlays s_v: dead by then)
    short* accP = (short*)(ws + 5 * BHT);            // 4 x BHT shorts (attn partials)
    short* s_y1 = (short*)(ws + 5 * BHT);            // f1 out (B,T,FFN), after attn consumed
    short* wqkv = (short*)(ws + 7 * BHT);            // [L][576][192]
    short* wo16 = wqkv + (size_t)LN * 3 * HN * HN;
    short* wp16 = wo16 + (size_t)LN * HN * HN;
    short* wf1_16 = wp16 + (size_t)2 * OUTN * HN;
    short* wf2_16 = wf1_16 + (size_t)LN * 3 * FFNN * HN;
    float* bqkv = (float*)(wf2_16 + (size_t)LN * 3 * FFNN * HN);  // [L][576]
    float* lP = bqkv + (size_t)LN * 576;             // 4 x B x NH x T floats

    // fused weight conversion (single launch)
    {
        long total = (long)LN * 576 * 192 + LN * 576 + LN * HN * HN + 2 * OUTN * HN
                   + 2L * LN * FFNN * HN * 3;
        k_cvtall<<<dim3((unsigned)((total + 255) / 256)), 256, 0, stream>>>(
            qw, kw, vw, qb, kb, vb, ow, pw, f1w, f2w,
            wqkv, bqkv, wo16, wp16, wf1_16, wf2_16);
    }

    dim3 gemb(TN / 16, BN);             // 64 x 8 (2 blocks/CU for token gather)
    k_embed<<<gemb, 256, 0, stream>>>(tok, lens, emb, x, s_xb);

    dim3 gqkv(TN / 128, 9, BN);         // 8 x 9 x 8 (512 thr)
    dim3 gattn(TN / 128, NHN * 4, BN);  // 8 x 8 x 8 (512-thread blocks)
    dim3 gol(TN / 32, BN);              // 32 x 8 (fused oproj+merge+LN1, 512 thr)
    dim3 gf1(TN / 128, FFNN / 64, BN);  // 8 x 12 x 8 (512 thr)
    dim3 gf2(TN / 128, 9, BN);          // 8 x (3m x 3kg) x 8 (512 thr)
    dim3 gln(TN / 32, BN);              // 32 x 8 (512 thr)

    for (int i = 0; i < LN; ++i) {
        const short* qkvwi = wqkv + (size_t)i * 576 * 192;
        const float* qkvbi = bqkv + (size_t)i * 576;
        const short* owi = wo16 + (size_t)i * HN * HN;
        const short* f1wi = wf1_16 + (size_t)i * 3 * FFNN * HN;
        const short* f2wi = wf2_16 + (size_t)i * 3 * FFNN * HN;
        const float* obi = ob + (size_t)i * HN;
        const float* rki = relk + (size_t)i * 9 * KCN;
        const float* rvi = relv + (size_t)i * 9 * KCN;
        const float* l1gi = ln1g + (size_t)i * HN;
        const float* l1bi = ln1b + (size_t)i * HN;
        const float* f1bi = f1b + (size_t)i * FFNN;
        const float* f2bi = f2b + (size_t)i * HN;
        const float* l2gi = ln2g + (size_t)i * HN;
        const float* l2bi = ln2b + (size_t)i * HN;

        k_qkv2<<<gqkv, 512, 0, stream>>>(qkvwi, s_xb, qkvbi, s_q, s_k, s_v, lens);
        k_attn4<<<gattn, 512, 0, stream>>>(s_q, s_k, s_v, rki, rvi, accP, lP, lens);
        k_oln<<<gol, 512, 0, stream>>>(owi, obi, accP, lP, x, l1gi, l1bi, s_ln, lens);
        k_mgemm<3, 128, true, true, 1, 1, false><<<gf1, 512, 0, stream>>>(
            f1wi, s_ln, f1bi, s_y1, nullptr, nullptr, lens, FFNN, HN);
        k_mgemm<3, 128, false, true, 0, 3, true><<<gf2, 512, 0, stream>>>(
            f2wi, s_y1, f2bi, s_yf, (float*)p1, (float*)p2, lens, HN, FFNN);
        k_ln<3><<<gln, 512, 0, stream>>>(x, s_yf, p1, p2, l2gi, l2bi, s_xb, lens);
    }

    dim3 gsf(TN / 64, OUTN / 64, BN);   // 16 x 3 x 8 (512 thr)
    k_statsfin<<<gsf, 512, 0, stream>>>(wp16, s_xb, pb, x, eps, lens, (float*)d_out);
}